// Round 20
// baseline (343.858 us; speedup 1.0000x reference)
//
#include <hip/hip_runtime.h>
#include <cstdint>
#include <cstddef>

// InvariantPointAttention N=768, H=12, C=384, PD=128, SQK=SV=16, PQK=4, PV=8.
// Round 20: R19 base (262.2us). fused res2d restructured: thread owns 2
// channels x 32 rows (quarter q=tid>>6) -> Pt broadcast reads halved
// (192->96 b128/thread/tile); att2d phase untouched (R16 frozen). comb now
// 3 quarters; rest verbatim.

#define N_RES 768
#define NHEAD 12
#define NN (768*768)

__device__ __forceinline__ float softplusf_(float x) {
  return (x > 20.f) ? x : log1pf(__expf(x));
}

// ---------------- pack B_all[384][1152] from 4 weight mats ------------------
__global__ __launch_bounds__(256) void pack_b_kernel(
    const float* __restrict__ wq, const float* __restrict__ wkv,
    const float* __restrict__ wqp, const float* __restrict__ wkvp,
    float* __restrict__ B_all)
{
  int idx4 = blockIdx.x * 256 + threadIdx.x;   // 110592 units
  int k = idx4 / 288;
  int n = (idx4 - k*288) * 4;
  float4 v;
  if (n < 192)       v = *(const float4*)(wq   + (size_t)k*192 + n);
  else if (n < 576)  v = *(const float4*)(wkv  + (size_t)k*384 + (n-192));
  else if (n < 720)  v = *(const float4*)(wqp  + (size_t)k*144 + (n-576));
  else               v = *(const float4*)(wkvp + (size_t)k*432 + (n-720));
  *(float4*)(B_all + (size_t)k*1152 + n) = v;
}

// ---------------- pack bias_all[1152] + wT[12][128] -------------------------
__global__ __launch_bounds__(256) void pack_small_kernel(
    const float* __restrict__ bq, const float* __restrict__ bkv,
    const float* __restrict__ bqp, const float* __restrict__ bkvp,
    const float* __restrict__ w2d,
    float* __restrict__ bias_all, float* __restrict__ wT)
{
  int idx = blockIdx.x * 256 + threadIdx.x;
  if (idx < 1152) {
    float v;
    if (idx < 192)      v = bq[idx];
    else if (idx < 576) v = bkv[idx-192];
    else if (idx < 720) v = bqp[idx-576];
    else                v = bkvp[idx-720];
    bias_all[idx] = v;
  } else if (idx < 2688) {
    int t = idx - 1152;
    int h = t >> 7, c = t & 127;
    wT[h*128 + c] = 0.5773502691896258f * w2d[c*12 + h];
  }
}

// ---------------- tiled GEMM, optional split-K ------------------------------
__global__ __launch_bounds__(256) void gemm_kernel(
    const float* __restrict__ A, int lda,
    const float* __restrict__ B, int ldb,
    const float* __restrict__ bias,
    float* __restrict__ C, int ldc,
    int M, int K, int kPerSplit)
{
  __shared__ float As[16][68];
  __shared__ float Bs[16][68];
  const int tid = threadIdx.x;
  const int m0 = blockIdx.y * 64, n0 = blockIdx.x * 64;
  const int kbeg = blockIdx.z * kPerSplit;
  const int kend = kbeg + kPerSplit;
  const int tn = tid & 15, tm = tid >> 4;
  float acc[4][4] = {};
  for (int k0 = kbeg; k0 < kend; k0 += 16) {
    {
      int idx = tid * 4;
      int m = idx >> 4, kk = idx & 15;
      float4 a = *(const float4*)(A + (size_t)(m0+m)*lda + k0 + kk);
      As[kk+0][m] = a.x; As[kk+1][m] = a.y; As[kk+2][m] = a.z; As[kk+3][m] = a.w;
    }
    {
      int kk = tid >> 4, n = (tid & 15) * 4;
      float4 b = *(const float4*)(B + (size_t)(k0+kk)*ldb + n0 + n);
      *(float4*)&Bs[kk][n] = b;
    }
    __syncthreads();
    #pragma unroll
    for (int k = 0; k < 16; ++k) {
      float4 a = *(const float4*)&As[k][tm*4];
      float4 b = *(const float4*)&Bs[k][tn*4];
      acc[0][0]=fmaf(a.x,b.x,acc[0][0]); acc[0][1]=fmaf(a.x,b.y,acc[0][1]);
      acc[0][2]=fmaf(a.x,b.z,acc[0][2]); acc[0][3]=fmaf(a.x,b.w,acc[0][3]);
      acc[1][0]=fmaf(a.y,b.x,acc[1][0]); acc[1][1]=fmaf(a.y,b.y,acc[1][1]);
      acc[1][2]=fmaf(a.y,b.z,acc[1][2]); acc[1][3]=fmaf(a.y,b.w,acc[1][3]);
      acc[2][0]=fmaf(a.z,b.x,acc[2][0]); acc[2][1]=fmaf(a.z,b.y,acc[2][1]);
      acc[2][2]=fmaf(a.z,b.z,acc[2][2]); acc[2][3]=fmaf(a.z,b.w,acc[2][3]);
      acc[3][0]=fmaf(a.w,b.x,acc[3][0]); acc[3][1]=fmaf(a.w,b.y,acc[3][1]);
      acc[3][2]=fmaf(a.w,b.z,acc[3][2]); acc[3][3]=fmaf(a.w,b.w,acc[3][3]);
    }
    __syncthreads();
  }
  float* Cp = C + (size_t)blockIdx.z * M * ldc;
  if (gridDim.z == 1) {
    #pragma unroll
    for (int r = 0; r < 4; ++r) {
      float* cp = Cp + (size_t)(m0 + tm*4 + r)*ldc + n0 + tn*4;
      #pragma unroll
      for (int c = 0; c < 4; ++c) cp[c] = acc[r][c] + bias[n0 + tn*4 + c];
    }
  } else {
    #pragma unroll
    for (int r = 0; r < 4; ++r) {
      float* cp = Cp + (size_t)(m0 + tm*4 + r)*ldc + n0 + tn*4;
      #pragma unroll
      for (int c = 0; c < 4; ++c) cp[c] = acc[r][c];
    }
  }
}

// ---------------- split-K reduce + bias -------------------------------------
__global__ __launch_bounds__(256) void reduce_out_kernel(
    const float* __restrict__ part, const float* __restrict__ bout,
    float* __restrict__ out)
{
  int idx4 = blockIdx.x * 256 + threadIdx.x;   // 73728 units
  if (idx4 >= 73728) return;
  int n4 = idx4 % 96;
  float4 a = *(const float4*)(bout + n4*4);
  #pragma unroll
  for (int z = 0; z < 6; ++z) {
    float4 p = *(const float4*)(part + (size_t)z*294912 + (size_t)idx4*4);
    a.x += p.x; a.y += p.y; a.z += p.z; a.w += p.w;
  }
  *(float4*)(out + (size_t)idx4*4) = a;
}

// ---------------- build packed U/K/V vectors --------------------------------
// U[h][i][32]: [sw*qs(16), pw*qpt(12), ci, 50*mi, -0.5*pw, 0]
// K[h][j][32]: [ks(16), kpt(12), 1, mj, kn, 0]
// V[j][h][40]: [vs(16), vpt(24, d*8+p)]
__global__ __launch_bounds__(256) void point_pack_kernel(
    const float* __restrict__ proj, const float* __restrict__ rot,
    const float* __restrict__ tra, const float* __restrict__ tpw,
    const float* __restrict__ b2d, const float* __restrict__ mask,
    float* __restrict__ Upack, float* __restrict__ Kpack, float* __restrict__ Vpack)
{
  int idx = blockIdx.x * 256 + threadIdx.x;
  if (idx >= N_RES * NHEAD) return;
  int i = idx / NHEAD, h = idx - i*NHEAD;
  float R[9], T[3];
  #pragma unroll
  for (int r = 0; r < 9; ++r) R[r] = rot[r*N_RES + i];
  #pragma unroll
  for (int d = 0; d < 3; ++d) T[d] = tra[d*N_RES + i];
  const float pw = 0.13608276348795434f * softplusf_(tpw[h]); // sqrt(1/54)*sp
  const float sw = 0.14433756729740643f;                      // sqrt(1/48)
  const float s3 = 0.5773502691896258f;                       // sqrt(1/3)
  const float* prow = proj + (size_t)i * 1152;
  float* U  = Upack + ((size_t)h * N_RES + i) * 32;
  float* Kp = Kpack + ((size_t)h * N_RES + i) * 32;
  float* Vp = Vpack + (size_t)idx * 40;
  #pragma unroll
  for (int c = 0; c < 16; ++c) U[c]  = sw * prow[h*16 + c];
  #pragma unroll
  for (int c = 0; c < 16; ++c) Kp[c] = prow[192 + h*32 + c];
  #pragma unroll
  for (int c = 0; c < 16; ++c) Vp[c] = prow[192 + h*32 + 16 + c];
  float qn = 0.f;
  #pragma unroll
  for (int p = 0; p < 4; ++p) {
    float x = prow[576      + h*4 + p];
    float y = prow[576 + 48 + h*4 + p];
    float z = prow[576 + 96 + h*4 + p];
    #pragma unroll
    for (int d = 0; d < 3; ++d) {
      float v = R[3*d]*x + R[3*d+1]*y + R[3*d+2]*z + T[d];
      U[16 + d*4 + p] = pw * v;
      qn += v*v;
    }
  }
  float kn = 0.f;
  #pragma unroll
  for (int m = 0; m < 12; ++m) {
    float x = prow[720       + h*12 + m];
    float y = prow[720 + 144 + h*12 + m];
    float z = prow[720 + 288 + h*12 + m];
    #pragma unroll
    for (int d = 0; d < 3; ++d) {
      float v = R[3*d]*x + R[3*d+1]*y + R[3*d+2]*z + T[d];
      if (m < 4) { Kp[16 + d*4 + m] = v; kn += v*v; }
      else       { Vp[16 + d*8 + (m-4)] = v; }
    }
  }
  U[28] = -0.5f*pw*qn + s3*b2d[h] - 50.f;  U[29] = 50.f * mask[i];
  U[30] = -0.5f*pw;                        U[31] = 0.f;
  Kp[28] = 1.f;   Kp[29] = mask[i];
  Kp[30] = kn;    Kp[31] = 0.f;
}

// ---------------- scalar+point logits: Lsp[h] = U[h] @ K[h]^T (rank 32) -----
__global__ __launch_bounds__(256) void logits_sp_kernel(
    const float* __restrict__ Upack, const float* __restrict__ Kpack,
    float* __restrict__ Lsp)
{
  __shared__ float Ut[64][33];
  __shared__ float Kt[64][33];
  const int h = blockIdx.z;
  const int i0 = blockIdx.y * 64, j0 = blockIdx.x * 64;
  const int tid = threadIdx.x;
  for (int t = tid; t < 512; t += 256) {
    int row = t >> 3, c4 = (t & 7) * 4;
    float4 u = *(const float4*)(Upack + ((size_t)h*N_RES + i0 + row)*32 + c4);
    float4 k = *(const float4*)(Kpack + ((size_t)h*N_RES + j0 + row)*32 + c4);
    Ut[row][c4+0]=u.x; Ut[row][c4+1]=u.y; Ut[row][c4+2]=u.z; Ut[row][c4+3]=u.w;
    Kt[row][c4+0]=k.x; Kt[row][c4+1]=k.y; Kt[row][c4+2]=k.z; Kt[row][c4+3]=k.w;
  }
  __syncthreads();
  const int tn = tid & 15, tm = tid >> 4;
  float acc[4][4] = {};
  #pragma unroll
  for (int k = 0; k < 32; ++k) {
    float a[4], b[4];
    #pragma unroll
    for (int r = 0; r < 4; ++r) a[r] = Ut[tm*4 + r][k];
    #pragma unroll
    for (int c = 0; c < 4; ++c) b[c] = Kt[tn*4 + c][k];
    #pragma unroll
    for (int r = 0; r < 4; ++r)
      #pragma unroll
      for (int c = 0; c < 4; ++c)
        acc[r][c] = fmaf(a[r], b[c], acc[r][c]);
  }
  #pragma unroll
  for (int r = 0; r < 4; ++r) {
    float4 v = make_float4(acc[r][0], acc[r][1], acc[r][2], acc[r][3]);
    *(float4*)(Lsp + (size_t)h*NN + (size_t)(i0 + tm*4 + r)*N_RES + j0 + tn*4) = v;
  }
}

// ---------------- fused: coalesced att2d + exp + res2d ----------------------
// grid 768 (block per i). att2d phase = R16 VERBATIM. res2d: thread owns 2
// channels (c2=(tid&63)*2) x 32 rows (quarter q=tid>>6) -> Pt reads halved;
// Pt reads stay wave-uniform broadcasts. 4-quarter combine via comb[3].
__global__ __launch_bounds__(256) void fused_attn_kernel(
    const float* __restrict__ in2d, const float* __restrict__ wT,
    float* __restrict__ logits,     // in: Lsp, out: P = exp(logit) (in-place)
    float* __restrict__ invS, float* __restrict__ feat)
{
  __shared__ __align__(16) float wTs[12][128];   // 6 KB
  __shared__ __align__(16) float Pt[128][12];    // 6 KB
  __shared__ float comb[3][12][128];             // 18 KB
  __shared__ float inv_sh[12];
  const int i = blockIdx.x;
  const int tid = threadIdx.x;
  const int wave = tid >> 6, lane = tid & 63;
  const int h0 = wave * 3;
  const int g = lane >> 2, t = lane & 3;
  for (int u = tid; u < 1536; u += 256) wTs[u >> 7][u & 127] = wT[u];
  __syncthreads();
  float s_run = 0.f;                 // head h0+t (t<3); t==3 unused
  const int c2 = (tid & 63) * 2, q = tid >> 6;
  float oacc[24];                    // [h*2 + k], k in {0,1}
  #pragma unroll
  for (int h = 0; h < 24; ++h) oacc[h] = 0.f;

  for (int jt = 0; jt < 6; ++jt) {
    const int j0 = jt * 128;
    // ---- att2d + logits + exp: 8 rounds x 16 j (R16 VERBATIM) ----
    #pragma unroll 2
    for (int r8 = 0; r8 < 8; ++r8) {
      const int j = j0 + r8*16 + g;
      const float* xrow = in2d + ((size_t)i*N_RES + j) * 128;
      float t0 = 0.f, t1 = 0.f, t2 = 0.f;
      #pragma unroll
      for (int c = 0; c < 8; ++c) {
        const int ch = c*16 + t*4;
        float4 x  = *(const float4*)(xrow + ch);
        float4 wa = *(const float4*)&wTs[h0+0][ch];
        float4 wb = *(const float4*)&wTs[h0+1][ch];
        float4 wc = *(const float4*)&wTs[h0+2][ch];
        t0 = fmaf(x.x,wa.x, fmaf(x.y,wa.y, fmaf(x.z,wa.z, fmaf(x.w,wa.w, t0))));
        t1 = fmaf(x.x,wb.x, fmaf(x.y,wb.y, fmaf(x.z,wb.z, fmaf(x.w,wb.w, t1))));
        t2 = fmaf(x.x,wc.x, fmaf(x.y,wc.y, fmaf(x.z,wc.z, fmaf(x.w,wc.w, t2))));
      }
      t0 += __shfl_xor(t0, 1); t0 += __shfl_xor(t0, 2);
      t1 += __shfl_xor(t1, 1); t1 += __shfl_xor(t1, 2);
      t2 += __shfl_xor(t2, 1); t2 += __shfl_xor(t2, 2);
      if (t < 3) {
        float td = (t == 0) ? t0 : ((t == 1) ? t1 : t2);
        const size_t off = (size_t)(h0+t)*NN + (size_t)i*N_RES + j;
        float l = logits[off] + td;
        float p = __expf(l);
        logits[off] = p;              // store P in place
        s_run += p;
        Pt[r8*16 + g][h0 + t] = p;
      }
    }
    __syncthreads();
    // ---- res2d: 2 channels (c2, c2+1), rows [q*32, q*32+32) ----
    {
      const float* xb = in2d + ((size_t)i*N_RES + j0 + q*32) * 128 + c2;
      #pragma unroll 4
      for (int jj = 0; jj < 32; ++jj) {
        int row = q*32 + jj;
        float2 x = *(const float2*)(xb + (size_t)jj * 128);
        float4 p0 = *(const float4*)&Pt[row][0];
        float4 p1 = *(const float4*)&Pt[row][4];
        float4 p2 = *(const float4*)&Pt[row][8];
        oacc[0]  = fmaf(p0.x, x.x, oacc[0]);  oacc[1]  = fmaf(p0.x, x.y, oacc[1]);
        oacc[2]  = fmaf(p0.y, x.x, oacc[2]);  oacc[3]  = fmaf(p0.y, x.y, oacc[3]);
        oacc[4]  = fmaf(p0.z, x.x, oacc[4]);  oacc[5]  = fmaf(p0.z, x.y, oacc[5]);
        oacc[6]  = fmaf(p0.w, x.x, oacc[6]);  oacc[7]  = fmaf(p0.w, x.y, oacc[7]);
        oacc[8]  = fmaf(p1.x, x.x, oacc[8]);  oacc[9]  = fmaf(p1.x, x.y, oacc[9]);
        oacc[10] = fmaf(p1.y, x.x, oacc[10]); oacc[11] = fmaf(p1.y, x.y, oacc[11]);
        oacc[12] = fmaf(p1.z, x.x, oacc[12]); oacc[13] = fmaf(p1.z, x.y, oacc[13]);
        oacc[14] = fmaf(p1.w, x.x, oacc[14]); oacc[15] = fmaf(p1.w, x.y, oacc[15]);
        oacc[16] = fmaf(p2.x, x.x, oacc[16]); oacc[17] = fmaf(p2.x, x.y, oacc[17]);
        oacc[18] = fmaf(p2.y, x.x, oacc[18]); oacc[19] = fmaf(p2.y, x.y, oacc[19]);
        oacc[20] = fmaf(p2.z, x.x, oacc[20]); oacc[21] = fmaf(p2.z, x.y, oacc[21]);
        oacc[22] = fmaf(p2.w, x.x, oacc[22]); oacc[23] = fmaf(p2.w, x.y, oacc[23]);
      }
    }
    __syncthreads();   // Pt consumed; safe to overwrite next iter
  }
  // ---- denominators: butterfly over g-bits (4,8,16,32), lanes 0..2 write ---
  {
    float s = s_run;
    s += __shfl_xor(s, 4);
    s += __shfl_xor(s, 8);
    s += __shfl_xor(s, 16);
    s += __shfl_xor(s, 32);
    if (g == 0 && t < 3) {
      float inv = 1.f / s;
      inv_sh[h0 + t] = inv;
      invS[(size_t)i*12 + h0 + t] = inv;
    }
  }
  if (q >= 1) {
    #pragma unroll
    for (int h = 0; h < 12; ++h) {
      comb[q-1][h][c2]   = oacc[h*2];
      comb[q-1][h][c2+1] = oacc[h*2+1];
    }
  }
  __syncthreads();
  if (q == 0) {
    float* f = feat + (size_t)i*2112 + 576;
    #pragma unroll
    for (int h = 0; h < 12; ++h) {
      float v0 = oacc[h*2]   + comb[0][h][c2]   + comb[1][h][c2]   + comb[2][h][c2];
      float v1 = oacc[h*2+1] + comb[0][h][c2+1] + comb[1][h][c2+1] + comb[2][h][c2+1];
      f[h*128 + c2]   = v0 * inv_sh[h];
      f[h*128 + c2+1] = v1 * inv_sh[h];
    }
  }
}

// ---------------- attn @ [vs | v_pt] per head -- b128 LDS reads -------------
__global__ __launch_bounds__(256) void res_sv_pt_kernel(
    const float* __restrict__ Pbuf, const float* __restrict__ invS,
    const float* __restrict__ Vpack, float* __restrict__ feat,
    float* __restrict__ rpt)
{
  __shared__ __align__(16) float at[16][132];
  __shared__ __align__(16) float vt[128][44];
  const int h = blockIdx.x;
  const int i0 = blockIdx.y * 16;
  const int tid = threadIdx.x;
  const int tm = tid / 10, tn = tid - tm*10;   // valid when tid < 160
  float acc[4] = {};
  for (int j0 = 0; j0 < 768; j0 += 128) {
    for (int t = tid; t < 16*32; t += 256) {
      int ii = t >> 5, jf = t & 31;
      float4 v = *(const float4*)(Pbuf + (size_t)h*NN + (size_t)(i0+ii)*N_RES + j0 + jf*4);
      float inv = invS[(size_t)(i0+ii)*12 + h];
      at[ii][jf*4+0] = v.x * inv;
      at[ii][jf*4+1] = v.y * inv;
      at[ii][jf*4+2] = v.z * inv;
      at[ii][jf*4+3] = v.w * inv;
    }
    for (int t = tid; t < 128*40; t += 256) {
      int jj = t / 40, c = t - jj*40;
      vt[jj][c] = Vpack[((size_t)(j0+jj)*12 + h)*40 + c];
    }
    __syncthreads();
    if (tid < 160) {
      #pragma unroll 4
      for (int jj0 = 0; jj0 < 128; jj0 += 4) {
        float4 a4 = *(const float4*)&at[tm][jj0];
        float4 v0 = *(const float4*)&vt[jj0+0][tn*4];
        float4 v1 = *(const float4*)&vt[jj0+1][tn*4];
        float4 v2 = *(const float4*)&vt[jj0+2][tn*4];
        float4 v3 = *(const float4*)&vt[jj0+3][tn*4];
        acc[0] = fmaf(a4.x, v0.x, acc[0]);
        acc[1] = fmaf(a4.x, v0.y, acc[1]);
        acc[2] = fmaf(a4.x, v0.z, acc[2]);
        acc[3] = fmaf(a4.x, v0.w, acc[3]);
        acc[0] = fmaf(a4.y, v1.x, acc[0]);
        acc[1] = fmaf(a4.y, v1.y, acc[1]);
        acc[2] = fmaf(a4.y, v1.z, acc[2]);
        acc[3] = fmaf(a4.y, v1.w, acc[3]);
        acc[0] = fmaf(a4.z, v2.x, acc[0]);
        acc[1] = fmaf(a4.z, v2.y, acc[1]);
        acc[2] = fmaf(a4.z, v2.z, acc[2]);
        acc[3] = fmaf(a4.z, v2.w, acc[3]);
        acc[0] = fmaf(a4.w, v3.x, acc[0]);
        acc[1] = fmaf(a4.w, v3.y, acc[1]);
        acc[2] = fmaf(a4.w, v3.z, acc[2]);
        acc[3] = fmaf(a4.w, v3.w, acc[3]);
      }
    }
    __syncthreads();
  }
  if (tid < 160) {
    const int i = i0 + tm;
    #pragma unroll
    for (int c = 0; c < 4; ++c) {
      int col = tn*4 + c;
      if (col < 16)      feat[(size_t)i*2112 + h*16 + col] = acc[c];
      else               rpt[((size_t)i*NHEAD + h)*24 + (col-16)] = acc[c];
    }
  }
}

// ---------------- point epilogue --------------------------------------------
__global__ __launch_bounds__(256) void pt_epilogue_kernel(
    const float* __restrict__ rpt,
    const float* __restrict__ rot, const float* __restrict__ tra,
    float* __restrict__ feat)
{
  int idx = blockIdx.x * 256 + threadIdx.x;
  if (idx >= N_RES * 96) return;
  int i = idx / 96, m = idx - i*96;
  int h = m >> 3, p = m & 7;
  const float* rp = rpt + ((size_t)i*NHEAD + h)*24 + p;
  float gx = rp[0]  - tra[i];
  float gy = rp[8]  - tra[N_RES + i];
  float gz = rp[16] - tra[2*N_RES + i];
  float lx = rot[0*N_RES+i]*gx + rot[3*N_RES+i]*gy + rot[6*N_RES+i]*gz;
  float ly = rot[1*N_RES+i]*gx + rot[4*N_RES+i]*gy + rot[7*N_RES+i]*gz;
  float lz = rot[2*N_RES+i]*gx + rot[5*N_RES+i]*gy + rot[8*N_RES+i]*gz;
  float dist = sqrtf(1e-8f + lx*lx + ly*ly + lz*lz);
  float* f = feat + (size_t)i*2112 + 192;
  f[m]       = lx;
  f[96 + m]  = ly;
  f[192 + m] = lz;
  f[288 + m] = dist;
}

extern "C" void kernel_launch(void* const* d_in, const int* in_sizes, int n_in,
                              void* d_out, int out_size, void* d_ws, size_t ws_size,
                              hipStream_t stream)
{
  const float* in1d = (const float*)d_in[0];
  const float* in2d = (const float*)d_in[1];
  const float* mask = (const float*)d_in[2];
  const float* rot  = (const float*)d_in[3];
  const float* tra  = (const float*)d_in[4];
  const float* wq   = (const float*)d_in[5];
  const float* bq   = (const float*)d_in[6];
  const float* wkv  = (const float*)d_in[7];
  const float* bkv  = (const float*)d_in[8];
  const float* wqp  = (const float*)d_in[9];
  const float* bqp  = (const float*)d_in[10];
  const float* wkvp = (const float*)d_in[11];
  const float* bkvp = (const float*)d_in[12];
  const float* tpw  = (const float*)d_in[13];
  const float* w2d  = (const float*)d_in[14];
  const float* b2d  = (const float*)d_in[15];
  const float* wout = (const float*)d_in[16];
  const float* bout = (const float*)d_in[17];
  float* out = (float*)d_out;

  float* ws = (float*)d_ws;
  float* Upack    = ws;                  // 294912
  float* Kpack    = ws + 294912;         // 294912  -> 589824
  float* Vpack    = ws + 589824;         // 368640  -> 958464
  float* wT       = ws + 958464;         // 1536    -> 960000
  float* feat     = ws + 960000;         // 1622016 -> 2582016
  float* invS     = ws + 2582016;        // 9216    -> 2591232
  float* rpt      = ws + 2591232;        // 221184  -> 2812416
  // region X at 2812416: proj_all(884736) | B_all(442368) | bias_all(1152)
  float* proj_all = ws + 2812416;        // dead after point_pack
  float* B_all    = ws + 3697152;        // dead after proj GEMM
  float* bias_all = ws + 4139520;        // dead after proj GEMM
  // logits aliases region X (written by logits_sp AFTER point_pack)
  float* logits   = ws + 2812416;        // 7077888 -> 9890304
  float* part     = ws + 2812416;        // 1769472 (out-GEMM partials, after res_sv_pt)
  // high-water: 9890304 floats = 39.6 MB

  pack_b_kernel<<<432, 256, 0, stream>>>(wq, wkv, wqp, wkvp, B_all);
  pack_small_kernel<<<11, 256, 0, stream>>>(bq, bkv, bqp, bkvp, w2d, bias_all, wT);
  gemm_kernel<<<dim3(18,12,1), 256, 0, stream>>>(in1d, 384, B_all, 1152, bias_all,
                                                 proj_all, 1152, 768, 384, 384);
  point_pack_kernel<<<36, 256, 0, stream>>>(proj_all, rot, tra, tpw, b2d, mask,
                                            Upack, Kpack, Vpack);
  logits_sp_kernel<<<dim3(12,12,12), 256, 0, stream>>>(Upack, Kpack, logits);
  fused_attn_kernel<<<N_RES, 256, 0, stream>>>(in2d, wT, logits, invS, feat);
  res_sv_pt_kernel<<<dim3(12,48), 256, 0, stream>>>(logits, invS, Vpack, feat, rpt);
  pt_epilogue_kernel<<<288, 256, 0, stream>>>(rpt, rot, tra, feat);
  gemm_kernel<<<dim3(6,12,6), 256, 0, stream>>>(feat, 2112, wout, 384, nullptr,
                                                part, 384, 768, 2112, 352);
  reduce_out_kernel<<<288, 256, 0, stream>>>(part, bout, out);
}

// Round 21
// 261.600 us; speedup vs baseline: 1.3144x; 1.3144x over previous
//
#include <hip/hip_runtime.h>
#include <cstdint>
#include <cstddef>

// InvariantPointAttention N=768, H=12, C=384, PD=128, SQK=SV=16, PQK=4, PV=8.
// Round 21: REVERT to R19 (262.2us proven best). R20's res2d remap regressed
// (7th failed structural edit on the fused round loop) -- the R16/R19 code
// shape is a hard local optimum; holding it as the final configuration.

#define N_RES 768
#define NHEAD 12
#define NN (768*768)

__device__ __forceinline__ float softplusf_(float x) {
  return (x > 20.f) ? x : log1pf(__expf(x));
}

// ---------------- pack B_all[384][1152] from 4 weight mats ------------------
__global__ __launch_bounds__(256) void pack_b_kernel(
    const float* __restrict__ wq, const float* __restrict__ wkv,
    const float* __restrict__ wqp, const float* __restrict__ wkvp,
    float* __restrict__ B_all)
{
  int idx4 = blockIdx.x * 256 + threadIdx.x;   // 110592 units
  int k = idx4 / 288;
  int n = (idx4 - k*288) * 4;
  float4 v;
  if (n < 192)       v = *(const float4*)(wq   + (size_t)k*192 + n);
  else if (n < 576)  v = *(const float4*)(wkv  + (size_t)k*384 + (n-192));
  else if (n < 720)  v = *(const float4*)(wqp  + (size_t)k*144 + (n-576));
  else               v = *(const float4*)(wkvp + (size_t)k*432 + (n-720));
  *(float4*)(B_all + (size_t)k*1152 + n) = v;
}

// ---------------- pack bias_all[1152] + wT[12][128] -------------------------
__global__ __launch_bounds__(256) void pack_small_kernel(
    const float* __restrict__ bq, const float* __restrict__ bkv,
    const float* __restrict__ bqp, const float* __restrict__ bkvp,
    const float* __restrict__ w2d,
    float* __restrict__ bias_all, float* __restrict__ wT)
{
  int idx = blockIdx.x * 256 + threadIdx.x;
  if (idx < 1152) {
    float v;
    if (idx < 192)      v = bq[idx];
    else if (idx < 576) v = bkv[idx-192];
    else if (idx < 720) v = bqp[idx-576];
    else                v = bkvp[idx-720];
    bias_all[idx] = v;
  } else if (idx < 2688) {
    int t = idx - 1152;
    int h = t >> 7, c = t & 127;
    wT[h*128 + c] = 0.5773502691896258f * w2d[c*12 + h];
  }
}

// ---------------- tiled GEMM, optional split-K ------------------------------
__global__ __launch_bounds__(256) void gemm_kernel(
    const float* __restrict__ A, int lda,
    const float* __restrict__ B, int ldb,
    const float* __restrict__ bias,
    float* __restrict__ C, int ldc,
    int M, int K, int kPerSplit)
{
  __shared__ float As[16][68];
  __shared__ float Bs[16][68];
  const int tid = threadIdx.x;
  const int m0 = blockIdx.y * 64, n0 = blockIdx.x * 64;
  const int kbeg = blockIdx.z * kPerSplit;
  const int kend = kbeg + kPerSplit;
  const int tn = tid & 15, tm = tid >> 4;
  float acc[4][4] = {};
  for (int k0 = kbeg; k0 < kend; k0 += 16) {
    {
      int idx = tid * 4;
      int m = idx >> 4, kk = idx & 15;
      float4 a = *(const float4*)(A + (size_t)(m0+m)*lda + k0 + kk);
      As[kk+0][m] = a.x; As[kk+1][m] = a.y; As[kk+2][m] = a.z; As[kk+3][m] = a.w;
    }
    {
      int kk = tid >> 4, n = (tid & 15) * 4;
      float4 b = *(const float4*)(B + (size_t)(k0+kk)*ldb + n0 + n);
      *(float4*)&Bs[kk][n] = b;
    }
    __syncthreads();
    #pragma unroll
    for (int k = 0; k < 16; ++k) {
      float4 a = *(const float4*)&As[k][tm*4];
      float4 b = *(const float4*)&Bs[k][tn*4];
      acc[0][0]=fmaf(a.x,b.x,acc[0][0]); acc[0][1]=fmaf(a.x,b.y,acc[0][1]);
      acc[0][2]=fmaf(a.x,b.z,acc[0][2]); acc[0][3]=fmaf(a.x,b.w,acc[0][3]);
      acc[1][0]=fmaf(a.y,b.x,acc[1][0]); acc[1][1]=fmaf(a.y,b.y,acc[1][1]);
      acc[1][2]=fmaf(a.y,b.z,acc[1][2]); acc[1][3]=fmaf(a.y,b.w,acc[1][3]);
      acc[2][0]=fmaf(a.z,b.x,acc[2][0]); acc[2][1]=fmaf(a.z,b.y,acc[2][1]);
      acc[2][2]=fmaf(a.z,b.z,acc[2][2]); acc[2][3]=fmaf(a.z,b.w,acc[2][3]);
      acc[3][0]=fmaf(a.w,b.x,acc[3][0]); acc[3][1]=fmaf(a.w,b.y,acc[3][1]);
      acc[3][2]=fmaf(a.w,b.z,acc[3][2]); acc[3][3]=fmaf(a.w,b.w,acc[3][3]);
    }
    __syncthreads();
  }
  float* Cp = C + (size_t)blockIdx.z * M * ldc;
  if (gridDim.z == 1) {
    #pragma unroll
    for (int r = 0; r < 4; ++r) {
      float* cp = Cp + (size_t)(m0 + tm*4 + r)*ldc + n0 + tn*4;
      #pragma unroll
      for (int c = 0; c < 4; ++c) cp[c] = acc[r][c] + bias[n0 + tn*4 + c];
    }
  } else {
    #pragma unroll
    for (int r = 0; r < 4; ++r) {
      float* cp = Cp + (size_t)(m0 + tm*4 + r)*ldc + n0 + tn*4;
      #pragma unroll
      for (int c = 0; c < 4; ++c) cp[c] = acc[r][c];
    }
  }
}

// ---------------- split-K reduce + bias -------------------------------------
__global__ __launch_bounds__(256) void reduce_out_kernel(
    const float* __restrict__ part, const float* __restrict__ bout,
    float* __restrict__ out)
{
  int idx4 = blockIdx.x * 256 + threadIdx.x;   // 73728 units
  if (idx4 >= 73728) return;
  int n4 = idx4 % 96;
  float4 a = *(const float4*)(bout + n4*4);
  #pragma unroll
  for (int z = 0; z < 6; ++z) {
    float4 p = *(const float4*)(part + (size_t)z*294912 + (size_t)idx4*4);
    a.x += p.x; a.y += p.y; a.z += p.z; a.w += p.w;
  }
  *(float4*)(out + (size_t)idx4*4) = a;
}

// ---------------- build packed U/K/V vectors --------------------------------
// U[h][i][32]: [sw*qs(16), pw*qpt(12), ci, 50*mi, -0.5*pw, 0]
// K[h][j][32]: [ks(16), kpt(12), 1, mj, kn, 0]
// V[j][h][40]: [vs(16), vpt(24, d*8+p)]
__global__ __launch_bounds__(256) void point_pack_kernel(
    const float* __restrict__ proj, const float* __restrict__ rot,
    const float* __restrict__ tra, const float* __restrict__ tpw,
    const float* __restrict__ b2d, const float* __restrict__ mask,
    float* __restrict__ Upack, float* __restrict__ Kpack, float* __restrict__ Vpack)
{
  int idx = blockIdx.x * 256 + threadIdx.x;
  if (idx >= N_RES * NHEAD) return;
  int i = idx / NHEAD, h = idx - i*NHEAD;
  float R[9], T[3];
  #pragma unroll
  for (int r = 0; r < 9; ++r) R[r] = rot[r*N_RES + i];
  #pragma unroll
  for (int d = 0; d < 3; ++d) T[d] = tra[d*N_RES + i];
  const float pw = 0.13608276348795434f * softplusf_(tpw[h]); // sqrt(1/54)*sp
  const float sw = 0.14433756729740643f;                      // sqrt(1/48)
  const float s3 = 0.5773502691896258f;                       // sqrt(1/3)
  const float* prow = proj + (size_t)i * 1152;
  float* U  = Upack + ((size_t)h * N_RES + i) * 32;
  float* Kp = Kpack + ((size_t)h * N_RES + i) * 32;
  float* Vp = Vpack + (size_t)idx * 40;
  #pragma unroll
  for (int c = 0; c < 16; ++c) U[c]  = sw * prow[h*16 + c];
  #pragma unroll
  for (int c = 0; c < 16; ++c) Kp[c] = prow[192 + h*32 + c];
  #pragma unroll
  for (int c = 0; c < 16; ++c) Vp[c] = prow[192 + h*32 + 16 + c];
  float qn = 0.f;
  #pragma unroll
  for (int p = 0; p < 4; ++p) {
    float x = prow[576      + h*4 + p];
    float y = prow[576 + 48 + h*4 + p];
    float z = prow[576 + 96 + h*4 + p];
    #pragma unroll
    for (int d = 0; d < 3; ++d) {
      float v = R[3*d]*x + R[3*d+1]*y + R[3*d+2]*z + T[d];
      U[16 + d*4 + p] = pw * v;
      qn += v*v;
    }
  }
  float kn = 0.f;
  #pragma unroll
  for (int m = 0; m < 12; ++m) {
    float x = prow[720       + h*12 + m];
    float y = prow[720 + 144 + h*12 + m];
    float z = prow[720 + 288 + h*12 + m];
    #pragma unroll
    for (int d = 0; d < 3; ++d) {
      float v = R[3*d]*x + R[3*d+1]*y + R[3*d+2]*z + T[d];
      if (m < 4) { Kp[16 + d*4 + m] = v; kn += v*v; }
      else       { Vp[16 + d*8 + (m-4)] = v; }
    }
  }
  U[28] = -0.5f*pw*qn + s3*b2d[h] - 50.f;  U[29] = 50.f * mask[i];
  U[30] = -0.5f*pw;                        U[31] = 0.f;
  Kp[28] = 1.f;   Kp[29] = mask[i];
  Kp[30] = kn;    Kp[31] = 0.f;
}

// ---------------- scalar+point logits: Lsp[h] = U[h] @ K[h]^T (rank 32) -----
__global__ __launch_bounds__(256) void logits_sp_kernel(
    const float* __restrict__ Upack, const float* __restrict__ Kpack,
    float* __restrict__ Lsp)
{
  __shared__ float Ut[64][33];
  __shared__ float Kt[64][33];
  const int h = blockIdx.z;
  const int i0 = blockIdx.y * 64, j0 = blockIdx.x * 64;
  const int tid = threadIdx.x;
  for (int t = tid; t < 512; t += 256) {
    int row = t >> 3, c4 = (t & 7) * 4;
    float4 u = *(const float4*)(Upack + ((size_t)h*N_RES + i0 + row)*32 + c4);
    float4 k = *(const float4*)(Kpack + ((size_t)h*N_RES + j0 + row)*32 + c4);
    Ut[row][c4+0]=u.x; Ut[row][c4+1]=u.y; Ut[row][c4+2]=u.z; Ut[row][c4+3]=u.w;
    Kt[row][c4+0]=k.x; Kt[row][c4+1]=k.y; Kt[row][c4+2]=k.z; Kt[row][c4+3]=k.w;
  }
  __syncthreads();
  const int tn = tid & 15, tm = tid >> 4;
  float acc[4][4] = {};
  #pragma unroll
  for (int k = 0; k < 32; ++k) {
    float a[4], b[4];
    #pragma unroll
    for (int r = 0; r < 4; ++r) a[r] = Ut[tm*4 + r][k];
    #pragma unroll
    for (int c = 0; c < 4; ++c) b[c] = Kt[tn*4 + c][k];
    #pragma unroll
    for (int r = 0; r < 4; ++r)
      #pragma unroll
      for (int c = 0; c < 4; ++c)
        acc[r][c] = fmaf(a[r], b[c], acc[r][c]);
  }
  #pragma unroll
  for (int r = 0; r < 4; ++r) {
    float4 v = make_float4(acc[r][0], acc[r][1], acc[r][2], acc[r][3]);
    *(float4*)(Lsp + (size_t)h*NN + (size_t)(i0 + tm*4 + r)*N_RES + j0 + tn*4) = v;
  }
}

// ---------------- fused: coalesced att2d + exp + res2d (R16 VERBATIM) -------
__global__ __launch_bounds__(256) void fused_attn_kernel(
    const float* __restrict__ in2d, const float* __restrict__ wT,
    float* __restrict__ logits,     // in: Lsp, out: P = exp(logit) (in-place)
    float* __restrict__ invS, float* __restrict__ feat)
{
  __shared__ __align__(16) float wTs[12][128];   // 6 KB
  __shared__ __align__(16) float Pt[128][12];    // 6 KB
  __shared__ float comb[12][128];                // 6 KB
  __shared__ float inv_sh[12];
  const int i = blockIdx.x;
  const int tid = threadIdx.x;
  const int wave = tid >> 6, lane = tid & 63;
  const int h0 = wave * 3;
  const int g = lane >> 2, t = lane & 3;
  for (int u = tid; u < 1536; u += 256) wTs[u >> 7][u & 127] = wT[u];
  __syncthreads();
  float s_run = 0.f;                 // head h0+t (t<3); t==3 unused
  const int oc = tid & 127, ohalf = tid >> 7;
  float oacc[12];
  #pragma unroll
  for (int h = 0; h < 12; ++h) oacc[h] = 0.f;

  for (int jt = 0; jt < 6; ++jt) {
    const int j0 = jt * 128;
    // ---- att2d + logits + exp: 8 rounds x 16 j ----
    #pragma unroll 2
    for (int r8 = 0; r8 < 8; ++r8) {
      const int j = j0 + r8*16 + g;
      const float* xrow = in2d + ((size_t)i*N_RES + j) * 128;
      float t0 = 0.f, t1 = 0.f, t2 = 0.f;
      #pragma unroll
      for (int c = 0; c < 8; ++c) {
        const int ch = c*16 + t*4;
        float4 x  = *(const float4*)(xrow + ch);
        float4 wa = *(const float4*)&wTs[h0+0][ch];
        float4 wb = *(const float4*)&wTs[h0+1][ch];
        float4 wc = *(const float4*)&wTs[h0+2][ch];
        t0 = fmaf(x.x,wa.x, fmaf(x.y,wa.y, fmaf(x.z,wa.z, fmaf(x.w,wa.w, t0))));
        t1 = fmaf(x.x,wb.x, fmaf(x.y,wb.y, fmaf(x.z,wb.z, fmaf(x.w,wb.w, t1))));
        t2 = fmaf(x.x,wc.x, fmaf(x.y,wc.y, fmaf(x.z,wc.z, fmaf(x.w,wc.w, t2))));
      }
      // butterfly over the 4-lane group
      t0 += __shfl_xor(t0, 1); t0 += __shfl_xor(t0, 2);
      t1 += __shfl_xor(t1, 1); t1 += __shfl_xor(t1, 2);
      t2 += __shfl_xor(t2, 1); t2 += __shfl_xor(t2, 2);
      if (t < 3) {
        float td = (t == 0) ? t0 : ((t == 1) ? t1 : t2);
        const size_t off = (size_t)(h0+t)*NN + (size_t)i*N_RES + j;
        float l = logits[off] + td;
        float p = __expf(l);
        logits[off] = p;              // store P in place
        s_run += p;
        Pt[r8*16 + g][h0 + t] = p;
      }
    }
    __syncthreads();
    // ---- res2d: 128 rows, thread handles rows [ohalf*64, +64), channel oc --
    {
      const float* xb = in2d + ((size_t)i*N_RES + j0 + ohalf*64) * 128 + oc;
      #pragma unroll 4
      for (int jj = 0; jj < 64; ++jj) {
        int row = ohalf*64 + jj;
        float x = xb[(size_t)jj * 128];
        float4 p0 = *(const float4*)&Pt[row][0];
        float4 p1 = *(const float4*)&Pt[row][4];
        float4 p2 = *(const float4*)&Pt[row][8];
        oacc[0] = fmaf(p0.x, x, oacc[0]);
        oacc[1] = fmaf(p0.y, x, oacc[1]);
        oacc[2] = fmaf(p0.z, x, oacc[2]);
        oacc[3] = fmaf(p0.w, x, oacc[3]);
        oacc[4] = fmaf(p1.x, x, oacc[4]);
        oacc[5] = fmaf(p1.y, x, oacc[5]);
        oacc[6] = fmaf(p1.z, x, oacc[6]);
        oacc[7] = fmaf(p1.w, x, oacc[7]);
        oacc[8] = fmaf(p2.x, x, oacc[8]);
        oacc[9] = fmaf(p2.y, x, oacc[9]);
        oacc[10] = fmaf(p2.z, x, oacc[10]);
        oacc[11] = fmaf(p2.w, x, oacc[11]);
      }
    }
    __syncthreads();   // Pt consumed; safe to overwrite next iter
  }
  // ---- denominators: butterfly over g-bits (4,8,16,32), lanes 0..2 write ---
  {
    float s = s_run;
    s += __shfl_xor(s, 4);
    s += __shfl_xor(s, 8);
    s += __shfl_xor(s, 16);
    s += __shfl_xor(s, 32);
    if (g == 0 && t < 3) {
      float inv = 1.f / s;
      inv_sh[h0 + t] = inv;
      invS[(size_t)i*12 + h0 + t] = inv;
    }
  }
  if (ohalf == 1) {
    #pragma unroll
    for (int h = 0; h < 12; ++h) comb[h][oc] = oacc[h];
  }
  __syncthreads();
  if (ohalf == 0) {
    float* f = feat + (size_t)i*2112 + 576;
    #pragma unroll
    for (int h = 0; h < 12; ++h)
      f[h*128 + oc] = (oacc[h] + comb[h][oc]) * inv_sh[h];
  }
}

// ---------------- attn @ [vs | v_pt] per head -- b128 LDS reads -------------
// grid (12,48), 256 thr. Compute: 160 active threads = 16 rows x 10 col-groups
// of 4 (cols 0..39). vt padded [128][44] (16B-aligned rows). Per 4-jj step:
// 1 at-b128 + 4 vt-b128. Accumulation ascending jj (order preserved).
__global__ __launch_bounds__(256) void res_sv_pt_kernel(
    const float* __restrict__ Pbuf, const float* __restrict__ invS,
    const float* __restrict__ Vpack, float* __restrict__ feat,
    float* __restrict__ rpt)
{
  __shared__ __align__(16) float at[16][132];
  __shared__ __align__(16) float vt[128][44];
  const int h = blockIdx.x;
  const int i0 = blockIdx.y * 16;
  const int tid = threadIdx.x;
  const int tm = tid / 10, tn = tid - tm*10;   // valid when tid < 160
  float acc[4] = {};
  for (int j0 = 0; j0 < 768; j0 += 128) {
    for (int t = tid; t < 16*32; t += 256) {
      int ii = t >> 5, jf = t & 31;
      float4 v = *(const float4*)(Pbuf + (size_t)h*NN + (size_t)(i0+ii)*N_RES + j0 + jf*4);
      float inv = invS[(size_t)(i0+ii)*12 + h];
      at[ii][jf*4+0] = v.x * inv;
      at[ii][jf*4+1] = v.y * inv;
      at[ii][jf*4+2] = v.z * inv;
      at[ii][jf*4+3] = v.w * inv;
    }
    for (int t = tid; t < 128*40; t += 256) {
      int jj = t / 40, c = t - jj*40;
      vt[jj][c] = Vpack[((size_t)(j0+jj)*12 + h)*40 + c];
    }
    __syncthreads();
    if (tid < 160) {
      #pragma unroll 4
      for (int jj0 = 0; jj0 < 128; jj0 += 4) {
        float4 a4 = *(const float4*)&at[tm][jj0];
        float4 v0 = *(const float4*)&vt[jj0+0][tn*4];
        float4 v1 = *(const float4*)&vt[jj0+1][tn*4];
        float4 v2 = *(const float4*)&vt[jj0+2][tn*4];
        float4 v3 = *(const float4*)&vt[jj0+3][tn*4];
        acc[0] = fmaf(a4.x, v0.x, acc[0]);
        acc[1] = fmaf(a4.x, v0.y, acc[1]);
        acc[2] = fmaf(a4.x, v0.z, acc[2]);
        acc[3] = fmaf(a4.x, v0.w, acc[3]);
        acc[0] = fmaf(a4.y, v1.x, acc[0]);
        acc[1] = fmaf(a4.y, v1.y, acc[1]);
        acc[2] = fmaf(a4.y, v1.z, acc[2]);
        acc[3] = fmaf(a4.y, v1.w, acc[3]);
        acc[0] = fmaf(a4.z, v2.x, acc[0]);
        acc[1] = fmaf(a4.z, v2.y, acc[1]);
        acc[2] = fmaf(a4.z, v2.z, acc[2]);
        acc[3] = fmaf(a4.z, v2.w, acc[3]);
        acc[0] = fmaf(a4.w, v3.x, acc[0]);
        acc[1] = fmaf(a4.w, v3.y, acc[1]);
        acc[2] = fmaf(a4.w, v3.z, acc[2]);
        acc[3] = fmaf(a4.w, v3.w, acc[3]);
      }
    }
    __syncthreads();
  }
  if (tid < 160) {
    const int i = i0 + tm;
    #pragma unroll
    for (int c = 0; c < 4; ++c) {
      int col = tn*4 + c;
      if (col < 16)      feat[(size_t)i*2112 + h*16 + col] = acc[c];
      else               rpt[((size_t)i*NHEAD + h)*24 + (col-16)] = acc[c];
    }
  }
}

// ---------------- point epilogue --------------------------------------------
__global__ __launch_bounds__(256) void pt_epilogue_kernel(
    const float* __restrict__ rpt,
    const float* __restrict__ rot, const float* __restrict__ tra,
    float* __restrict__ feat)
{
  int idx = blockIdx.x * 256 + threadIdx.x;
  if (idx >= N_RES * 96) return;
  int i = idx / 96, m = idx - i*96;
  int h = m >> 3, p = m & 7;
  const float* rp = rpt + ((size_t)i*NHEAD + h)*24 + p;
  float gx = rp[0]  - tra[i];
  float gy = rp[8]  - tra[N_RES + i];
  float gz = rp[16] - tra[2*N_RES + i];
  float lx = rot[0*N_RES+i]*gx + rot[3*N_RES+i]*gy + rot[6*N_RES+i]*gz;
  float ly = rot[1*N_RES+i]*gx + rot[4*N_RES+i]*gy + rot[7*N_RES+i]*gz;
  float lz = rot[2*N_RES+i]*gx + rot[5*N_RES+i]*gy + rot[8*N_RES+i]*gz;
  float dist = sqrtf(1e-8f + lx*lx + ly*ly + lz*lz);
  float* f = feat + (size_t)i*2112 + 192;
  f[m]       = lx;
  f[96 + m]  = ly;
  f[192 + m] = lz;
  f[288 + m] = dist;
}

extern "C" void kernel_launch(void* const* d_in, const int* in_sizes, int n_in,
                              void* d_out, int out_size, void* d_ws, size_t ws_size,
                              hipStream_t stream)
{
  const float* in1d = (const float*)d_in[0];
  const float* in2d = (const float*)d_in[1];
  const float* mask = (const float*)d_in[2];
  const float* rot  = (const float*)d_in[3];
  const float* tra  = (const float*)d_in[4];
  const float* wq   = (const float*)d_in[5];
  const float* bq   = (const float*)d_in[6];
  const float* wkv  = (const float*)d_in[7];
  const float* bkv  = (const float*)d_in[8];
  const float* wqp  = (const float*)d_in[9];
  const float* bqp  = (const float*)d_in[10];
  const float* wkvp = (const float*)d_in[11];
  const float* bkvp = (const float*)d_in[12];
  const float* tpw  = (const float*)d_in[13];
  const float* w2d  = (const float*)d_in[14];
  const float* b2d  = (const float*)d_in[15];
  const float* wout = (const float*)d_in[16];
  const float* bout = (const float*)d_in[17];
  float* out = (float*)d_out;

  float* ws = (float*)d_ws;
  float* Upack    = ws;                  // 294912
  float* Kpack    = ws + 294912;         // 294912  -> 589824
  float* Vpack    = ws + 589824;         // 368640  -> 958464
  float* wT       = ws + 958464;         // 1536    -> 960000
  float* feat     = ws + 960000;         // 1622016 -> 2582016
  float* invS     = ws + 2582016;        // 9216    -> 2591232
  float* rpt      = ws + 2591232;        // 221184  -> 2812416
  // region X at 2812416: proj_all(884736) | B_all(442368) | bias_all(1152)
  float* proj_all = ws + 2812416;        // dead after point_pack
  float* B_all    = ws + 3697152;        // dead after proj GEMM
  float* bias_all = ws + 4139520;        // dead after proj GEMM
  // logits aliases region X (written by logits_sp AFTER point_pack)
  float* logits   = ws + 2812416;        // 7077888 -> 9890304
  float* part     = ws + 2812416;        // 1769472 (out-GEMM partials, after res_sv_pt)
  // high-water: 9890304 floats = 39.6 MB

  pack_b_kernel<<<432, 256, 0, stream>>>(wq, wkv, wqp, wkvp, B_all);
  pack_small_kernel<<<11, 256, 0, stream>>>(bq, bkv, bqp, bkvp, w2d, bias_all, wT);
  gemm_kernel<<<dim3(18,12,1), 256, 0, stream>>>(in1d, 384, B_all, 1152, bias_all,
                                                 proj_all, 1152, 768, 384, 384);
  point_pack_kernel<<<36, 256, 0, stream>>>(proj_all, rot, tra, tpw, b2d, mask,
                                            Upack, Kpack, Vpack);
  logits_sp_kernel<<<dim3(12,12,12), 256, 0, stream>>>(Upack, Kpack, logits);
  fused_attn_kernel<<<N_RES, 256, 0, stream>>>(in2d, wT, logits, invS, feat);
  res_sv_pt_kernel<<<dim3(12,48), 256, 0, stream>>>(logits, invS, Vpack, feat, rpt);
  pt_epilogue_kernel<<<288, 256, 0, stream>>>(rpt, rot, tra, feat);
  gemm_kernel<<<dim3(6,12,6), 256, 0, stream>>>(feat, 2112, wout, 384, nullptr,
                                                part, 384, 768, 2112, 352);
  reduce_out_kernel<<<288, 256, 0, stream>>>(part, bout, out);
}

// Round 22
// 258.455 us; speedup vs baseline: 1.3304x; 1.0122x over previous
//
#include <hip/hip_runtime.h>
#include <cstdint>
#include <cstddef>

// InvariantPointAttention N=768, H=12, C=384, PD=128, SQK=SV=16, PQK=4, PV=8.
// Round 22: R21 base (261.6us proven). One low-risk edit: logits_sp LDS tiles
// stored k-major [32][68] so the rank-32 inner loop reads 2x ds_read_b128 per
// k (was 8x b32) -- the same-shape b128 vectorization that won in R2/R19.
// Ascending-k accumulation preserved (bitwise-identical Lsp). All else frozen.

#define N_RES 768
#define NHEAD 12
#define NN (768*768)

__device__ __forceinline__ float softplusf_(float x) {
  return (x > 20.f) ? x : log1pf(__expf(x));
}

// ---------------- pack B_all[384][1152] from 4 weight mats ------------------
__global__ __launch_bounds__(256) void pack_b_kernel(
    const float* __restrict__ wq, const float* __restrict__ wkv,
    const float* __restrict__ wqp, const float* __restrict__ wkvp,
    float* __restrict__ B_all)
{
  int idx4 = blockIdx.x * 256 + threadIdx.x;   // 110592 units
  int k = idx4 / 288;
  int n = (idx4 - k*288) * 4;
  float4 v;
  if (n < 192)       v = *(const float4*)(wq   + (size_t)k*192 + n);
  else if (n < 576)  v = *(const float4*)(wkv  + (size_t)k*384 + (n-192));
  else if (n < 720)  v = *(const float4*)(wqp  + (size_t)k*144 + (n-576));
  else               v = *(const float4*)(wkvp + (size_t)k*432 + (n-720));
  *(float4*)(B_all + (size_t)k*1152 + n) = v;
}

// ---------------- pack bias_all[1152] + wT[12][128] -------------------------
__global__ __launch_bounds__(256) void pack_small_kernel(
    const float* __restrict__ bq, const float* __restrict__ bkv,
    const float* __restrict__ bqp, const float* __restrict__ bkvp,
    const float* __restrict__ w2d,
    float* __restrict__ bias_all, float* __restrict__ wT)
{
  int idx = blockIdx.x * 256 + threadIdx.x;
  if (idx < 1152) {
    float v;
    if (idx < 192)      v = bq[idx];
    else if (idx < 576) v = bkv[idx-192];
    else if (idx < 720) v = bqp[idx-576];
    else                v = bkvp[idx-720];
    bias_all[idx] = v;
  } else if (idx < 2688) {
    int t = idx - 1152;
    int h = t >> 7, c = t & 127;
    wT[h*128 + c] = 0.5773502691896258f * w2d[c*12 + h];
  }
}

// ---------------- tiled GEMM, optional split-K ------------------------------
__global__ __launch_bounds__(256) void gemm_kernel(
    const float* __restrict__ A, int lda,
    const float* __restrict__ B, int ldb,
    const float* __restrict__ bias,
    float* __restrict__ C, int ldc,
    int M, int K, int kPerSplit)
{
  __shared__ float As[16][68];
  __shared__ float Bs[16][68];
  const int tid = threadIdx.x;
  const int m0 = blockIdx.y * 64, n0 = blockIdx.x * 64;
  const int kbeg = blockIdx.z * kPerSplit;
  const int kend = kbeg + kPerSplit;
  const int tn = tid & 15, tm = tid >> 4;
  float acc[4][4] = {};
  for (int k0 = kbeg; k0 < kend; k0 += 16) {
    {
      int idx = tid * 4;
      int m = idx >> 4, kk = idx & 15;
      float4 a = *(const float4*)(A + (size_t)(m0+m)*lda + k0 + kk);
      As[kk+0][m] = a.x; As[kk+1][m] = a.y; As[kk+2][m] = a.z; As[kk+3][m] = a.w;
    }
    {
      int kk = tid >> 4, n = (tid & 15) * 4;
      float4 b = *(const float4*)(B + (size_t)(k0+kk)*ldb + n0 + n);
      *(float4*)&Bs[kk][n] = b;
    }
    __syncthreads();
    #pragma unroll
    for (int k = 0; k < 16; ++k) {
      float4 a = *(const float4*)&As[k][tm*4];
      float4 b = *(const float4*)&Bs[k][tn*4];
      acc[0][0]=fmaf(a.x,b.x,acc[0][0]); acc[0][1]=fmaf(a.x,b.y,acc[0][1]);
      acc[0][2]=fmaf(a.x,b.z,acc[0][2]); acc[0][3]=fmaf(a.x,b.w,acc[0][3]);
      acc[1][0]=fmaf(a.y,b.x,acc[1][0]); acc[1][1]=fmaf(a.y,b.y,acc[1][1]);
      acc[1][2]=fmaf(a.y,b.z,acc[1][2]); acc[1][3]=fmaf(a.y,b.w,acc[1][3]);
      acc[2][0]=fmaf(a.z,b.x,acc[2][0]); acc[2][1]=fmaf(a.z,b.y,acc[2][1]);
      acc[2][2]=fmaf(a.z,b.z,acc[2][2]); acc[2][3]=fmaf(a.z,b.w,acc[2][3]);
      acc[3][0]=fmaf(a.w,b.x,acc[3][0]); acc[3][1]=fmaf(a.w,b.y,acc[3][1]);
      acc[3][2]=fmaf(a.w,b.z,acc[3][2]); acc[3][3]=fmaf(a.w,b.w,acc[3][3]);
    }
    __syncthreads();
  }
  float* Cp = C + (size_t)blockIdx.z * M * ldc;
  if (gridDim.z == 1) {
    #pragma unroll
    for (int r = 0; r < 4; ++r) {
      float* cp = Cp + (size_t)(m0 + tm*4 + r)*ldc + n0 + tn*4;
      #pragma unroll
      for (int c = 0; c < 4; ++c) cp[c] = acc[r][c] + bias[n0 + tn*4 + c];
    }
  } else {
    #pragma unroll
    for (int r = 0; r < 4; ++r) {
      float* cp = Cp + (size_t)(m0 + tm*4 + r)*ldc + n0 + tn*4;
      #pragma unroll
      for (int c = 0; c < 4; ++c) cp[c] = acc[r][c];
    }
  }
}

// ---------------- split-K reduce + bias -------------------------------------
__global__ __launch_bounds__(256) void reduce_out_kernel(
    const float* __restrict__ part, const float* __restrict__ bout,
    float* __restrict__ out)
{
  int idx4 = blockIdx.x * 256 + threadIdx.x;   // 73728 units
  if (idx4 >= 73728) return;
  int n4 = idx4 % 96;
  float4 a = *(const float4*)(bout + n4*4);
  #pragma unroll
  for (int z = 0; z < 6; ++z) {
    float4 p = *(const float4*)(part + (size_t)z*294912 + (size_t)idx4*4);
    a.x += p.x; a.y += p.y; a.z += p.z; a.w += p.w;
  }
  *(float4*)(out + (size_t)idx4*4) = a;
}

// ---------------- build packed U/K/V vectors --------------------------------
// U[h][i][32]: [sw*qs(16), pw*qpt(12), ci, 50*mi, -0.5*pw, 0]
// K[h][j][32]: [ks(16), kpt(12), 1, mj, kn, 0]
// V[j][h][40]: [vs(16), vpt(24, d*8+p)]
__global__ __launch_bounds__(256) void point_pack_kernel(
    const float* __restrict__ proj, const float* __restrict__ rot,
    const float* __restrict__ tra, const float* __restrict__ tpw,
    const float* __restrict__ b2d, const float* __restrict__ mask,
    float* __restrict__ Upack, float* __restrict__ Kpack, float* __restrict__ Vpack)
{
  int idx = blockIdx.x * 256 + threadIdx.x;
  if (idx >= N_RES * NHEAD) return;
  int i = idx / NHEAD, h = idx - i*NHEAD;
  float R[9], T[3];
  #pragma unroll
  for (int r = 0; r < 9; ++r) R[r] = rot[r*N_RES + i];
  #pragma unroll
  for (int d = 0; d < 3; ++d) T[d] = tra[d*N_RES + i];
  const float pw = 0.13608276348795434f * softplusf_(tpw[h]); // sqrt(1/54)*sp
  const float sw = 0.14433756729740643f;                      // sqrt(1/48)
  const float s3 = 0.5773502691896258f;                       // sqrt(1/3)
  const float* prow = proj + (size_t)i * 1152;
  float* U  = Upack + ((size_t)h * N_RES + i) * 32;
  float* Kp = Kpack + ((size_t)h * N_RES + i) * 32;
  float* Vp = Vpack + (size_t)idx * 40;
  #pragma unroll
  for (int c = 0; c < 16; ++c) U[c]  = sw * prow[h*16 + c];
  #pragma unroll
  for (int c = 0; c < 16; ++c) Kp[c] = prow[192 + h*32 + c];
  #pragma unroll
  for (int c = 0; c < 16; ++c) Vp[c] = prow[192 + h*32 + 16 + c];
  float qn = 0.f;
  #pragma unroll
  for (int p = 0; p < 4; ++p) {
    float x = prow[576      + h*4 + p];
    float y = prow[576 + 48 + h*4 + p];
    float z = prow[576 + 96 + h*4 + p];
    #pragma unroll
    for (int d = 0; d < 3; ++d) {
      float v = R[3*d]*x + R[3*d+1]*y + R[3*d+2]*z + T[d];
      U[16 + d*4 + p] = pw * v;
      qn += v*v;
    }
  }
  float kn = 0.f;
  #pragma unroll
  for (int m = 0; m < 12; ++m) {
    float x = prow[720       + h*12 + m];
    float y = prow[720 + 144 + h*12 + m];
    float z = prow[720 + 288 + h*12 + m];
    #pragma unroll
    for (int d = 0; d < 3; ++d) {
      float v = R[3*d]*x + R[3*d+1]*y + R[3*d+2]*z + T[d];
      if (m < 4) { Kp[16 + d*4 + m] = v; kn += v*v; }
      else       { Vp[16 + d*8 + (m-4)] = v; }
    }
  }
  U[28] = -0.5f*pw*qn + s3*b2d[h] - 50.f;  U[29] = 50.f * mask[i];
  U[30] = -0.5f*pw;                        U[31] = 0.f;
  Kp[28] = 1.f;   Kp[29] = mask[i];
  Kp[30] = kn;    Kp[31] = 0.f;
}

// ---------------- scalar+point logits: Lsp[h] = U[h] @ K[h]^T (rank 32) -----
// k-major LDS tiles [32][68] (272B rows, 16B-aligned at tm*4): inner loop is
// 2x ds_read_b128 per k (a = broadcast, b = stride-16B conflict-free).
__global__ __launch_bounds__(256) void logits_sp_kernel(
    const float* __restrict__ Upack, const float* __restrict__ Kpack,
    float* __restrict__ Lsp)
{
  __shared__ __align__(16) float Ut[32][68];
  __shared__ __align__(16) float Kt[32][68];
  const int h = blockIdx.z;
  const int i0 = blockIdx.y * 64, j0 = blockIdx.x * 64;
  const int tid = threadIdx.x;
  for (int t = tid; t < 512; t += 256) {
    int row = t >> 3, c4 = (t & 7) * 4;
    float4 u = *(const float4*)(Upack + ((size_t)h*N_RES + i0 + row)*32 + c4);
    float4 k = *(const float4*)(Kpack + ((size_t)h*N_RES + j0 + row)*32 + c4);
    Ut[c4+0][row] = u.x; Ut[c4+1][row] = u.y; Ut[c4+2][row] = u.z; Ut[c4+3][row] = u.w;
    Kt[c4+0][row] = k.x; Kt[c4+1][row] = k.y; Kt[c4+2][row] = k.z; Kt[c4+3][row] = k.w;
  }
  __syncthreads();
  const int tn = tid & 15, tm = tid >> 4;
  float acc[4][4] = {};
  #pragma unroll
  for (int k = 0; k < 32; ++k) {
    float4 a = *(const float4*)&Ut[k][tm*4];
    float4 b = *(const float4*)&Kt[k][tn*4];
    acc[0][0]=fmaf(a.x,b.x,acc[0][0]); acc[0][1]=fmaf(a.x,b.y,acc[0][1]);
    acc[0][2]=fmaf(a.x,b.z,acc[0][2]); acc[0][3]=fmaf(a.x,b.w,acc[0][3]);
    acc[1][0]=fmaf(a.y,b.x,acc[1][0]); acc[1][1]=fmaf(a.y,b.y,acc[1][1]);
    acc[1][2]=fmaf(a.y,b.z,acc[1][2]); acc[1][3]=fmaf(a.y,b.w,acc[1][3]);
    acc[2][0]=fmaf(a.z,b.x,acc[2][0]); acc[2][1]=fmaf(a.z,b.y,acc[2][1]);
    acc[2][2]=fmaf(a.z,b.z,acc[2][2]); acc[2][3]=fmaf(a.z,b.w,acc[2][3]);
    acc[3][0]=fmaf(a.w,b.x,acc[3][0]); acc[3][1]=fmaf(a.w,b.y,acc[3][1]);
    acc[3][2]=fmaf(a.w,b.z,acc[3][2]); acc[3][3]=fmaf(a.w,b.w,acc[3][3]);
  }
  #pragma unroll
  for (int r = 0; r < 4; ++r) {
    float4 v = make_float4(acc[r][0], acc[r][1], acc[r][2], acc[r][3]);
    *(float4*)(Lsp + (size_t)h*NN + (size_t)(i0 + tm*4 + r)*N_RES + j0 + tn*4) = v;
  }
}

// ---------------- fused: coalesced att2d + exp + res2d (R16 VERBATIM) -------
__global__ __launch_bounds__(256) void fused_attn_kernel(
    const float* __restrict__ in2d, const float* __restrict__ wT,
    float* __restrict__ logits,     // in: Lsp, out: P = exp(logit) (in-place)
    float* __restrict__ invS, float* __restrict__ feat)
{
  __shared__ __align__(16) float wTs[12][128];   // 6 KB
  __shared__ __align__(16) float Pt[128][12];    // 6 KB
  __shared__ float comb[12][128];                // 6 KB
  __shared__ float inv_sh[12];
  const int i = blockIdx.x;
  const int tid = threadIdx.x;
  const int wave = tid >> 6, lane = tid & 63;
  const int h0 = wave * 3;
  const int g = lane >> 2, t = lane & 3;
  for (int u = tid; u < 1536; u += 256) wTs[u >> 7][u & 127] = wT[u];
  __syncthreads();
  float s_run = 0.f;                 // head h0+t (t<3); t==3 unused
  const int oc = tid & 127, ohalf = tid >> 7;
  float oacc[12];
  #pragma unroll
  for (int h = 0; h < 12; ++h) oacc[h] = 0.f;

  for (int jt = 0; jt < 6; ++jt) {
    const int j0 = jt * 128;
    // ---- att2d + logits + exp: 8 rounds x 16 j ----
    #pragma unroll 2
    for (int r8 = 0; r8 < 8; ++r8) {
      const int j = j0 + r8*16 + g;
      const float* xrow = in2d + ((size_t)i*N_RES + j) * 128;
      float t0 = 0.f, t1 = 0.f, t2 = 0.f;
      #pragma unroll
      for (int c = 0; c < 8; ++c) {
        const int ch = c*16 + t*4;
        float4 x  = *(const float4*)(xrow + ch);
        float4 wa = *(const float4*)&wTs[h0+0][ch];
        float4 wb = *(const float4*)&wTs[h0+1][ch];
        float4 wc = *(const float4*)&wTs[h0+2][ch];
        t0 = fmaf(x.x,wa.x, fmaf(x.y,wa.y, fmaf(x.z,wa.z, fmaf(x.w,wa.w, t0))));
        t1 = fmaf(x.x,wb.x, fmaf(x.y,wb.y, fmaf(x.z,wb.z, fmaf(x.w,wb.w, t1))));
        t2 = fmaf(x.x,wc.x, fmaf(x.y,wc.y, fmaf(x.z,wc.z, fmaf(x.w,wc.w, t2))));
      }
      // butterfly over the 4-lane group
      t0 += __shfl_xor(t0, 1); t0 += __shfl_xor(t0, 2);
      t1 += __shfl_xor(t1, 1); t1 += __shfl_xor(t1, 2);
      t2 += __shfl_xor(t2, 1); t2 += __shfl_xor(t2, 2);
      if (t < 3) {
        float td = (t == 0) ? t0 : ((t == 1) ? t1 : t2);
        const size_t off = (size_t)(h0+t)*NN + (size_t)i*N_RES + j;
        float l = logits[off] + td;
        float p = __expf(l);
        logits[off] = p;              // store P in place
        s_run += p;
        Pt[r8*16 + g][h0 + t] = p;
      }
    }
    __syncthreads();
    // ---- res2d: 128 rows, thread handles rows [ohalf*64, +64), channel oc --
    {
      const float* xb = in2d + ((size_t)i*N_RES + j0 + ohalf*64) * 128 + oc;
      #pragma unroll 4
      for (int jj = 0; jj < 64; ++jj) {
        int row = ohalf*64 + jj;
        float x = xb[(size_t)jj * 128];
        float4 p0 = *(const float4*)&Pt[row][0];
        float4 p1 = *(const float4*)&Pt[row][4];
        float4 p2 = *(const float4*)&Pt[row][8];
        oacc[0] = fmaf(p0.x, x, oacc[0]);
        oacc[1] = fmaf(p0.y, x, oacc[1]);
        oacc[2] = fmaf(p0.z, x, oacc[2]);
        oacc[3] = fmaf(p0.w, x, oacc[3]);
        oacc[4] = fmaf(p1.x, x, oacc[4]);
        oacc[5] = fmaf(p1.y, x, oacc[5]);
        oacc[6] = fmaf(p1.z, x, oacc[6]);
        oacc[7] = fmaf(p1.w, x, oacc[7]);
        oacc[8] = fmaf(p2.x, x, oacc[8]);
        oacc[9] = fmaf(p2.y, x, oacc[9]);
        oacc[10] = fmaf(p2.z, x, oacc[10]);
        oacc[11] = fmaf(p2.w, x, oacc[11]);
      }
    }
    __syncthreads();   // Pt consumed; safe to overwrite next iter
  }
  // ---- denominators: butterfly over g-bits (4,8,16,32), lanes 0..2 write ---
  {
    float s = s_run;
    s += __shfl_xor(s, 4);
    s += __shfl_xor(s, 8);
    s += __shfl_xor(s, 16);
    s += __shfl_xor(s, 32);
    if (g == 0 && t < 3) {
      float inv = 1.f / s;
      inv_sh[h0 + t] = inv;
      invS[(size_t)i*12 + h0 + t] = inv;
    }
  }
  if (ohalf == 1) {
    #pragma unroll
    for (int h = 0; h < 12; ++h) comb[h][oc] = oacc[h];
  }
  __syncthreads();
  if (ohalf == 0) {
    float* f = feat + (size_t)i*2112 + 576;
    #pragma unroll
    for (int h = 0; h < 12; ++h)
      f[h*128 + oc] = (oacc[h] + comb[h][oc]) * inv_sh[h];
  }
}

// ---------------- attn @ [vs | v_pt] per head -- b128 LDS reads -------------
__global__ __launch_bounds__(256) void res_sv_pt_kernel(
    const float* __restrict__ Pbuf, const float* __restrict__ invS,
    const float* __restrict__ Vpack, float* __restrict__ feat,
    float* __restrict__ rpt)
{
  __shared__ __align__(16) float at[16][132];
  __shared__ __align__(16) float vt[128][44];
  const int h = blockIdx.x;
  const int i0 = blockIdx.y * 16;
  const int tid = threadIdx.x;
  const int tm = tid / 10, tn = tid - tm*10;   // valid when tid < 160
  float acc[4] = {};
  for (int j0 = 0; j0 < 768; j0 += 128) {
    for (int t = tid; t < 16*32; t += 256) {
      int ii = t >> 5, jf = t & 31;
      float4 v = *(const float4*)(Pbuf + (size_t)h*NN + (size_t)(i0+ii)*N_RES + j0 + jf*4);
      float inv = invS[(size_t)(i0+ii)*12 + h];
      at[ii][jf*4+0] = v.x * inv;
      at[ii][jf*4+1] = v.y * inv;
      at[ii][jf*4+2] = v.z * inv;
      at[ii][jf*4+3] = v.w * inv;
    }
    for (int t = tid; t < 128*40; t += 256) {
      int jj = t / 40, c = t - jj*40;
      vt[jj][c] = Vpack[((size_t)(j0+jj)*12 + h)*40 + c];
    }
    __syncthreads();
    if (tid < 160) {
      #pragma unroll 4
      for (int jj0 = 0; jj0 < 128; jj0 += 4) {
        float4 a4 = *(const float4*)&at[tm][jj0];
        float4 v0 = *(const float4*)&vt[jj0+0][tn*4];
        float4 v1 = *(const float4*)&vt[jj0+1][tn*4];
        float4 v2 = *(const float4*)&vt[jj0+2][tn*4];
        float4 v3 = *(const float4*)&vt[jj0+3][tn*4];
        acc[0] = fmaf(a4.x, v0.x, acc[0]);
        acc[1] = fmaf(a4.x, v0.y, acc[1]);
        acc[2] = fmaf(a4.x, v0.z, acc[2]);
        acc[3] = fmaf(a4.x, v0.w, acc[3]);
        acc[0] = fmaf(a4.y, v1.x, acc[0]);
        acc[1] = fmaf(a4.y, v1.y, acc[1]);
        acc[2] = fmaf(a4.y, v1.z, acc[2]);
        acc[3] = fmaf(a4.y, v1.w, acc[3]);
        acc[0] = fmaf(a4.z, v2.x, acc[0]);
        acc[1] = fmaf(a4.z, v2.y, acc[1]);
        acc[2] = fmaf(a4.z, v2.z, acc[2]);
        acc[3] = fmaf(a4.z, v2.w, acc[3]);
        acc[0] = fmaf(a4.w, v3.x, acc[0]);
        acc[1] = fmaf(a4.w, v3.y, acc[1]);
        acc[2] = fmaf(a4.w, v3.z, acc[2]);
        acc[3] = fmaf(a4.w, v3.w, acc[3]);
      }
    }
    __syncthreads();
  }
  if (tid < 160) {
    const int i = i0 + tm;
    #pragma unroll
    for (int c = 0; c < 4; ++c) {
      int col = tn*4 + c;
      if (col < 16)      feat[(size_t)i*2112 + h*16 + col] = acc[c];
      else               rpt[((size_t)i*NHEAD + h)*24 + (col-16)] = acc[c];
    }
  }
}

// ---------------- point epilogue --------------------------------------------
__global__ __launch_bounds__(256) void pt_epilogue_kernel(
    const float* __restrict__ rpt,
    const float* __restrict__ rot, const float* __restrict__ tra,
    float* __restrict__ feat)
{
  int idx = blockIdx.x * 256 + threadIdx.x;
  if (idx >= N_RES * 96) return;
  int i = idx / 96, m = idx - i*96;
  int h = m >> 3, p = m & 7;
  const float* rp = rpt + ((size_t)i*NHEAD + h)*24 + p;
  float gx = rp[0]  - tra[i];
  float gy = rp[8]  - tra[N_RES + i];
  float gz = rp[16] - tra[2*N_RES + i];
  float lx = rot[0*N_RES+i]*gx + rot[3*N_RES+i]*gy + rot[6*N_RES+i]*gz;
  float ly = rot[1*N_RES+i]*gx + rot[4*N_RES+i]*gy + rot[7*N_RES+i]*gz;
  float lz = rot[2*N_RES+i]*gx + rot[5*N_RES+i]*gy + rot[8*N_RES+i]*gz;
  float dist = sqrtf(1e-8f + lx*lx + ly*ly + lz*lz);
  float* f = feat + (size_t)i*2112 + 192;
  f[m]       = lx;
  f[96 + m]  = ly;
  f[192 + m] = lz;
  f[288 + m] = dist;
}

extern "C" void kernel_launch(void* const* d_in, const int* in_sizes, int n_in,
                              void* d_out, int out_size, void* d_ws, size_t ws_size,
                              hipStream_t stream)
{
  const float* in1d = (const float*)d_in[0];
  const float* in2d = (const float*)d_in[1];
  const float* mask = (const float*)d_in[2];
  const float* rot  = (const float*)d_in[3];
  const float* tra  = (const float*)d_in[4];
  const float* wq   = (const float*)d_in[5];
  const float* bq   = (const float*)d_in[6];
  const float* wkv  = (const float*)d_in[7];
  const float* bkv  = (const float*)d_in[8];
  const float* wqp  = (const float*)d_in[9];
  const float* bqp  = (const float*)d_in[10];
  const float* wkvp = (const float*)d_in[11];
  const float* bkvp = (const float*)d_in[12];
  const float* tpw  = (const float*)d_in[13];
  const float* w2d  = (const float*)d_in[14];
  const float* b2d  = (const float*)d_in[15];
  const float* wout = (const float*)d_in[16];
  const float* bout = (const float*)d_in[17];
  float* out = (float*)d_out;

  float* ws = (float*)d_ws;
  float* Upack    = ws;                  // 294912
  float* Kpack    = ws + 294912;         // 294912  -> 589824
  float* Vpack    = ws + 589824;         // 368640  -> 958464
  float* wT       = ws + 958464;         // 1536    -> 960000
  float* feat     = ws + 960000;         // 1622016 -> 2582016
  float* invS     = ws + 2582016;        // 9216    -> 2591232
  float* rpt      = ws + 2591232;        // 221184  -> 2812416
  // region X at 2812416: proj_all(884736) | B_all(442368) | bias_all(1152)
  float* proj_all = ws + 2812416;        // dead after point_pack
  float* B_all    = ws + 3697152;        // dead after proj GEMM
  float* bias_all = ws + 4139520;        // dead after proj GEMM
  // logits aliases region X (written by logits_sp AFTER point_pack)
  float* logits   = ws + 2812416;        // 7077888 -> 9890304
  float* part     = ws + 2812416;        // 1769472 (out-GEMM partials, after res_sv_pt)
  // high-water: 9890304 floats = 39.6 MB

  pack_b_kernel<<<432, 256, 0, stream>>>(wq, wkv, wqp, wkvp, B_all);
  pack_small_kernel<<<11, 256, 0, stream>>>(bq, bkv, bqp, bkvp, w2d, bias_all, wT);
  gemm_kernel<<<dim3(18,12,1), 256, 0, stream>>>(in1d, 384, B_all, 1152, bias_all,
                                                 proj_all, 1152, 768, 384, 384);
  point_pack_kernel<<<36, 256, 0, stream>>>(proj_all, rot, tra, tpw, b2d, mask,
                                            Upack, Kpack, Vpack);
  logits_sp_kernel<<<dim3(12,12,12), 256, 0, stream>>>(Upack, Kpack, logits);
  fused_attn_kernel<<<N_RES, 256, 0, stream>>>(in2d, wT, logits, invS, feat);
  res_sv_pt_kernel<<<dim3(12,48), 256, 0, stream>>>(logits, invS, Vpack, feat, rpt);
  pt_epilogue_kernel<<<288, 256, 0, stream>>>(rpt, rot, tra, feat);
  gemm_kernel<<<dim3(6,12,6), 256, 0, stream>>>(feat, 2112, wout, 384, nullptr,
                                                part, 384, 768, 2112, 352);
  reduce_out_kernel<<<288, 256, 0, stream>>>(part, bout, out);
}

// Round 23
// 255.275 us; speedup vs baseline: 1.3470x; 1.0125x over previous
//
#include <hip/hip_runtime.h>
#include <cstdint>
#include <cstddef>

// InvariantPointAttention N=768, H=12, C=384, PD=128, SQK=SV=16, PQK=4, PV=8.
// Round 23: R22 base (258.5us proven). Parameter-only edit: output GEMM
// split-K z=6 -> z=12 (432 -> 864 blocks, 1.7 -> 3.4 blocks/CU) to lift the
// last latency-starved kernel; reduce loops 12 partials. All else frozen.

#define N_RES 768
#define NHEAD 12
#define NN (768*768)
#define OUT_SPLIT 12

__device__ __forceinline__ float softplusf_(float x) {
  return (x > 20.f) ? x : log1pf(__expf(x));
}

// ---------------- pack B_all[384][1152] from 4 weight mats ------------------
__global__ __launch_bounds__(256) void pack_b_kernel(
    const float* __restrict__ wq, const float* __restrict__ wkv,
    const float* __restrict__ wqp, const float* __restrict__ wkvp,
    float* __restrict__ B_all)
{
  int idx4 = blockIdx.x * 256 + threadIdx.x;   // 110592 units
  int k = idx4 / 288;
  int n = (idx4 - k*288) * 4;
  float4 v;
  if (n < 192)       v = *(const float4*)(wq   + (size_t)k*192 + n);
  else if (n < 576)  v = *(const float4*)(wkv  + (size_t)k*384 + (n-192));
  else if (n < 720)  v = *(const float4*)(wqp  + (size_t)k*144 + (n-576));
  else               v = *(const float4*)(wkvp + (size_t)k*432 + (n-720));
  *(float4*)(B_all + (size_t)k*1152 + n) = v;
}

// ---------------- pack bias_all[1152] + wT[12][128] -------------------------
__global__ __launch_bounds__(256) void pack_small_kernel(
    const float* __restrict__ bq, const float* __restrict__ bkv,
    const float* __restrict__ bqp, const float* __restrict__ bkvp,
    const float* __restrict__ w2d,
    float* __restrict__ bias_all, float* __restrict__ wT)
{
  int idx = blockIdx.x * 256 + threadIdx.x;
  if (idx < 1152) {
    float v;
    if (idx < 192)      v = bq[idx];
    else if (idx < 576) v = bkv[idx-192];
    else if (idx < 720) v = bqp[idx-576];
    else                v = bkvp[idx-720];
    bias_all[idx] = v;
  } else if (idx < 2688) {
    int t = idx - 1152;
    int h = t >> 7, c = t & 127;
    wT[h*128 + c] = 0.5773502691896258f * w2d[c*12 + h];
  }
}

// ---------------- tiled GEMM, optional split-K ------------------------------
__global__ __launch_bounds__(256) void gemm_kernel(
    const float* __restrict__ A, int lda,
    const float* __restrict__ B, int ldb,
    const float* __restrict__ bias,
    float* __restrict__ C, int ldc,
    int M, int K, int kPerSplit)
{
  __shared__ float As[16][68];
  __shared__ float Bs[16][68];
  const int tid = threadIdx.x;
  const int m0 = blockIdx.y * 64, n0 = blockIdx.x * 64;
  const int kbeg = blockIdx.z * kPerSplit;
  const int kend = kbeg + kPerSplit;
  const int tn = tid & 15, tm = tid >> 4;
  float acc[4][4] = {};
  for (int k0 = kbeg; k0 < kend; k0 += 16) {
    {
      int idx = tid * 4;
      int m = idx >> 4, kk = idx & 15;
      float4 a = *(const float4*)(A + (size_t)(m0+m)*lda + k0 + kk);
      As[kk+0][m] = a.x; As[kk+1][m] = a.y; As[kk+2][m] = a.z; As[kk+3][m] = a.w;
    }
    {
      int kk = tid >> 4, n = (tid & 15) * 4;
      float4 b = *(const float4*)(B + (size_t)(k0+kk)*ldb + n0 + n);
      *(float4*)&Bs[kk][n] = b;
    }
    __syncthreads();
    #pragma unroll
    for (int k = 0; k < 16; ++k) {
      float4 a = *(const float4*)&As[k][tm*4];
      float4 b = *(const float4*)&Bs[k][tn*4];
      acc[0][0]=fmaf(a.x,b.x,acc[0][0]); acc[0][1]=fmaf(a.x,b.y,acc[0][1]);
      acc[0][2]=fmaf(a.x,b.z,acc[0][2]); acc[0][3]=fmaf(a.x,b.w,acc[0][3]);
      acc[1][0]=fmaf(a.y,b.x,acc[1][0]); acc[1][1]=fmaf(a.y,b.y,acc[1][1]);
      acc[1][2]=fmaf(a.y,b.z,acc[1][2]); acc[1][3]=fmaf(a.y,b.w,acc[1][3]);
      acc[2][0]=fmaf(a.z,b.x,acc[2][0]); acc[2][1]=fmaf(a.z,b.y,acc[2][1]);
      acc[2][2]=fmaf(a.z,b.z,acc[2][2]); acc[2][3]=fmaf(a.z,b.w,acc[2][3]);
      acc[3][0]=fmaf(a.w,b.x,acc[3][0]); acc[3][1]=fmaf(a.w,b.y,acc[3][1]);
      acc[3][2]=fmaf(a.w,b.z,acc[3][2]); acc[3][3]=fmaf(a.w,b.w,acc[3][3]);
    }
    __syncthreads();
  }
  float* Cp = C + (size_t)blockIdx.z * M * ldc;
  if (gridDim.z == 1) {
    #pragma unroll
    for (int r = 0; r < 4; ++r) {
      float* cp = Cp + (size_t)(m0 + tm*4 + r)*ldc + n0 + tn*4;
      #pragma unroll
      for (int c = 0; c < 4; ++c) cp[c] = acc[r][c] + bias[n0 + tn*4 + c];
    }
  } else {
    #pragma unroll
    for (int r = 0; r < 4; ++r) {
      float* cp = Cp + (size_t)(m0 + tm*4 + r)*ldc + n0 + tn*4;
      #pragma unroll
      for (int c = 0; c < 4; ++c) cp[c] = acc[r][c];
    }
  }
}

// ---------------- split-K reduce + bias (12 partials) -----------------------
__global__ __launch_bounds__(256) void reduce_out_kernel(
    const float* __restrict__ part, const float* __restrict__ bout,
    float* __restrict__ out)
{
  int idx4 = blockIdx.x * 256 + threadIdx.x;   // 73728 units
  if (idx4 >= 73728) return;
  int n4 = idx4 % 96;
  float4 a = *(const float4*)(bout + n4*4);
  #pragma unroll
  for (int z = 0; z < OUT_SPLIT; ++z) {
    float4 p = *(const float4*)(part + (size_t)z*294912 + (size_t)idx4*4);
    a.x += p.x; a.y += p.y; a.z += p.z; a.w += p.w;
  }
  *(float4*)(out + (size_t)idx4*4) = a;
}

// ---------------- build packed U/K/V vectors --------------------------------
// U[h][i][32]: [sw*qs(16), pw*qpt(12), ci, 50*mi, -0.5*pw, 0]
// K[h][j][32]: [ks(16), kpt(12), 1, mj, kn, 0]
// V[j][h][40]: [vs(16), vpt(24, d*8+p)]
__global__ __launch_bounds__(256) void point_pack_kernel(
    const float* __restrict__ proj, const float* __restrict__ rot,
    const float* __restrict__ tra, const float* __restrict__ tpw,
    const float* __restrict__ b2d, const float* __restrict__ mask,
    float* __restrict__ Upack, float* __restrict__ Kpack, float* __restrict__ Vpack)
{
  int idx = blockIdx.x * 256 + threadIdx.x;
  if (idx >= N_RES * NHEAD) return;
  int i = idx / NHEAD, h = idx - i*NHEAD;
  float R[9], T[3];
  #pragma unroll
  for (int r = 0; r < 9; ++r) R[r] = rot[r*N_RES + i];
  #pragma unroll
  for (int d = 0; d < 3; ++d) T[d] = tra[d*N_RES + i];
  const float pw = 0.13608276348795434f * softplusf_(tpw[h]); // sqrt(1/54)*sp
  const float sw = 0.14433756729740643f;                      // sqrt(1/48)
  const float s3 = 0.5773502691896258f;                       // sqrt(1/3)
  const float* prow = proj + (size_t)i * 1152;
  float* U  = Upack + ((size_t)h * N_RES + i) * 32;
  float* Kp = Kpack + ((size_t)h * N_RES + i) * 32;
  float* Vp = Vpack + (size_t)idx * 40;
  #pragma unroll
  for (int c = 0; c < 16; ++c) U[c]  = sw * prow[h*16 + c];
  #pragma unroll
  for (int c = 0; c < 16; ++c) Kp[c] = prow[192 + h*32 + c];
  #pragma unroll
  for (int c = 0; c < 16; ++c) Vp[c] = prow[192 + h*32 + 16 + c];
  float qn = 0.f;
  #pragma unroll
  for (int p = 0; p < 4; ++p) {
    float x = prow[576      + h*4 + p];
    float y = prow[576 + 48 + h*4 + p];
    float z = prow[576 + 96 + h*4 + p];
    #pragma unroll
    for (int d = 0; d < 3; ++d) {
      float v = R[3*d]*x + R[3*d+1]*y + R[3*d+2]*z + T[d];
      U[16 + d*4 + p] = pw * v;
      qn += v*v;
    }
  }
  float kn = 0.f;
  #pragma unroll
  for (int m = 0; m < 12; ++m) {
    float x = prow[720       + h*12 + m];
    float y = prow[720 + 144 + h*12 + m];
    float z = prow[720 + 288 + h*12 + m];
    #pragma unroll
    for (int d = 0; d < 3; ++d) {
      float v = R[3*d]*x + R[3*d+1]*y + R[3*d+2]*z + T[d];
      if (m < 4) { Kp[16 + d*4 + m] = v; kn += v*v; }
      else       { Vp[16 + d*8 + (m-4)] = v; }
    }
  }
  U[28] = -0.5f*pw*qn + s3*b2d[h] - 50.f;  U[29] = 50.f * mask[i];
  U[30] = -0.5f*pw;                        U[31] = 0.f;
  Kp[28] = 1.f;   Kp[29] = mask[i];
  Kp[30] = kn;    Kp[31] = 0.f;
}

// ---------------- scalar+point logits: Lsp[h] = U[h] @ K[h]^T (rank 32) -----
// k-major LDS tiles [32][68]: 2x ds_read_b128 per k (R22 proven).
__global__ __launch_bounds__(256) void logits_sp_kernel(
    const float* __restrict__ Upack, const float* __restrict__ Kpack,
    float* __restrict__ Lsp)
{
  __shared__ __align__(16) float Ut[32][68];
  __shared__ __align__(16) float Kt[32][68];
  const int h = blockIdx.z;
  const int i0 = blockIdx.y * 64, j0 = blockIdx.x * 64;
  const int tid = threadIdx.x;
  for (int t = tid; t < 512; t += 256) {
    int row = t >> 3, c4 = (t & 7) * 4;
    float4 u = *(const float4*)(Upack + ((size_t)h*N_RES + i0 + row)*32 + c4);
    float4 k = *(const float4*)(Kpack + ((size_t)h*N_RES + j0 + row)*32 + c4);
    Ut[c4+0][row] = u.x; Ut[c4+1][row] = u.y; Ut[c4+2][row] = u.z; Ut[c4+3][row] = u.w;
    Kt[c4+0][row] = k.x; Kt[c4+1][row] = k.y; Kt[c4+2][row] = k.z; Kt[c4+3][row] = k.w;
  }
  __syncthreads();
  const int tn = tid & 15, tm = tid >> 4;
  float acc[4][4] = {};
  #pragma unroll
  for (int k = 0; k < 32; ++k) {
    float4 a = *(const float4*)&Ut[k][tm*4];
    float4 b = *(const float4*)&Kt[k][tn*4];
    acc[0][0]=fmaf(a.x,b.x,acc[0][0]); acc[0][1]=fmaf(a.x,b.y,acc[0][1]);
    acc[0][2]=fmaf(a.x,b.z,acc[0][2]); acc[0][3]=fmaf(a.x,b.w,acc[0][3]);
    acc[1][0]=fmaf(a.y,b.x,acc[1][0]); acc[1][1]=fmaf(a.y,b.y,acc[1][1]);
    acc[1][2]=fmaf(a.y,b.z,acc[1][2]); acc[1][3]=fmaf(a.y,b.w,acc[1][3]);
    acc[2][0]=fmaf(a.z,b.x,acc[2][0]); acc[2][1]=fmaf(a.z,b.y,acc[2][1]);
    acc[2][2]=fmaf(a.z,b.z,acc[2][2]); acc[2][3]=fmaf(a.z,b.w,acc[2][3]);
    acc[3][0]=fmaf(a.w,b.x,acc[3][0]); acc[3][1]=fmaf(a.w,b.y,acc[3][1]);
    acc[3][2]=fmaf(a.w,b.z,acc[3][2]); acc[3][3]=fmaf(a.w,b.w,acc[3][3]);
  }
  #pragma unroll
  for (int r = 0; r < 4; ++r) {
    float4 v = make_float4(acc[r][0], acc[r][1], acc[r][2], acc[r][3]);
    *(float4*)(Lsp + (size_t)h*NN + (size_t)(i0 + tm*4 + r)*N_RES + j0 + tn*4) = v;
  }
}

// ---------------- fused: coalesced att2d + exp + res2d (R16 VERBATIM) -------
__global__ __launch_bounds__(256) void fused_attn_kernel(
    const float* __restrict__ in2d, const float* __restrict__ wT,
    float* __restrict__ logits,     // in: Lsp, out: P = exp(logit) (in-place)
    float* __restrict__ invS, float* __restrict__ feat)
{
  __shared__ __align__(16) float wTs[12][128];   // 6 KB
  __shared__ __align__(16) float Pt[128][12];    // 6 KB
  __shared__ float comb[12][128];                // 6 KB
  __shared__ float inv_sh[12];
  const int i = blockIdx.x;
  const int tid = threadIdx.x;
  const int wave = tid >> 6, lane = tid & 63;
  const int h0 = wave * 3;
  const int g = lane >> 2, t = lane & 3;
  for (int u = tid; u < 1536; u += 256) wTs[u >> 7][u & 127] = wT[u];
  __syncthreads();
  float s_run = 0.f;                 // head h0+t (t<3); t==3 unused
  const int oc = tid & 127, ohalf = tid >> 7;
  float oacc[12];
  #pragma unroll
  for (int h = 0; h < 12; ++h) oacc[h] = 0.f;

  for (int jt = 0; jt < 6; ++jt) {
    const int j0 = jt * 128;
    // ---- att2d + logits + exp: 8 rounds x 16 j ----
    #pragma unroll 2
    for (int r8 = 0; r8 < 8; ++r8) {
      const int j = j0 + r8*16 + g;
      const float* xrow = in2d + ((size_t)i*N_RES + j) * 128;
      float t0 = 0.f, t1 = 0.f, t2 = 0.f;
      #pragma unroll
      for (int c = 0; c < 8; ++c) {
        const int ch = c*16 + t*4;
        float4 x  = *(const float4*)(xrow + ch);
        float4 wa = *(const float4*)&wTs[h0+0][ch];
        float4 wb = *(const float4*)&wTs[h0+1][ch];
        float4 wc = *(const float4*)&wTs[h0+2][ch];
        t0 = fmaf(x.x,wa.x, fmaf(x.y,wa.y, fmaf(x.z,wa.z, fmaf(x.w,wa.w, t0))));
        t1 = fmaf(x.x,wb.x, fmaf(x.y,wb.y, fmaf(x.z,wb.z, fmaf(x.w,wb.w, t1))));
        t2 = fmaf(x.x,wc.x, fmaf(x.y,wc.y, fmaf(x.z,wc.z, fmaf(x.w,wc.w, t2))));
      }
      // butterfly over the 4-lane group
      t0 += __shfl_xor(t0, 1); t0 += __shfl_xor(t0, 2);
      t1 += __shfl_xor(t1, 1); t1 += __shfl_xor(t1, 2);
      t2 += __shfl_xor(t2, 1); t2 += __shfl_xor(t2, 2);
      if (t < 3) {
        float td = (t == 0) ? t0 : ((t == 1) ? t1 : t2);
        const size_t off = (size_t)(h0+t)*NN + (size_t)i*N_RES + j;
        float l = logits[off] + td;
        float p = __expf(l);
        logits[off] = p;              // store P in place
        s_run += p;
        Pt[r8*16 + g][h0 + t] = p;
      }
    }
    __syncthreads();
    // ---- res2d: 128 rows, thread handles rows [ohalf*64, +64), channel oc --
    {
      const float* xb = in2d + ((size_t)i*N_RES + j0 + ohalf*64) * 128 + oc;
      #pragma unroll 4
      for (int jj = 0; jj < 64; ++jj) {
        int row = ohalf*64 + jj;
        float x = xb[(size_t)jj * 128];
        float4 p0 = *(const float4*)&Pt[row][0];
        float4 p1 = *(const float4*)&Pt[row][4];
        float4 p2 = *(const float4*)&Pt[row][8];
        oacc[0] = fmaf(p0.x, x, oacc[0]);
        oacc[1] = fmaf(p0.y, x, oacc[1]);
        oacc[2] = fmaf(p0.z, x, oacc[2]);
        oacc[3] = fmaf(p0.w, x, oacc[3]);
        oacc[4] = fmaf(p1.x, x, oacc[4]);
        oacc[5] = fmaf(p1.y, x, oacc[5]);
        oacc[6] = fmaf(p1.z, x, oacc[6]);
        oacc[7] = fmaf(p1.w, x, oacc[7]);
        oacc[8] = fmaf(p2.x, x, oacc[8]);
        oacc[9] = fmaf(p2.y, x, oacc[9]);
        oacc[10] = fmaf(p2.z, x, oacc[10]);
        oacc[11] = fmaf(p2.w, x, oacc[11]);
      }
    }
    __syncthreads();   // Pt consumed; safe to overwrite next iter
  }
  // ---- denominators: butterfly over g-bits (4,8,16,32), lanes 0..2 write ---
  {
    float s = s_run;
    s += __shfl_xor(s, 4);
    s += __shfl_xor(s, 8);
    s += __shfl_xor(s, 16);
    s += __shfl_xor(s, 32);
    if (g == 0 && t < 3) {
      float inv = 1.f / s;
      inv_sh[h0 + t] = inv;
      invS[(size_t)i*12 + h0 + t] = inv;
    }
  }
  if (ohalf == 1) {
    #pragma unroll
    for (int h = 0; h < 12; ++h) comb[h][oc] = oacc[h];
  }
  __syncthreads();
  if (ohalf == 0) {
    float* f = feat + (size_t)i*2112 + 576;
    #pragma unroll
    for (int h = 0; h < 12; ++h)
      f[h*128 + oc] = (oacc[h] + comb[h][oc]) * inv_sh[h];
  }
}

// ---------------- attn @ [vs | v_pt] per head -- b128 LDS reads -------------
__global__ __launch_bounds__(256) void res_sv_pt_kernel(
    const float* __restrict__ Pbuf, const float* __restrict__ invS,
    const float* __restrict__ Vpack, float* __restrict__ feat,
    float* __restrict__ rpt)
{
  __shared__ __align__(16) float at[16][132];
  __shared__ __align__(16) float vt[128][44];
  const int h = blockIdx.x;
  const int i0 = blockIdx.y * 16;
  const int tid = threadIdx.x;
  const int tm = tid / 10, tn = tid - tm*10;   // valid when tid < 160
  float acc[4] = {};
  for (int j0 = 0; j0 < 768; j0 += 128) {
    for (int t = tid; t < 16*32; t += 256) {
      int ii = t >> 5, jf = t & 31;
      float4 v = *(const float4*)(Pbuf + (size_t)h*NN + (size_t)(i0+ii)*N_RES + j0 + jf*4);
      float inv = invS[(size_t)(i0+ii)*12 + h];
      at[ii][jf*4+0] = v.x * inv;
      at[ii][jf*4+1] = v.y * inv;
      at[ii][jf*4+2] = v.z * inv;
      at[ii][jf*4+3] = v.w * inv;
    }
    for (int t = tid; t < 128*40; t += 256) {
      int jj = t / 40, c = t - jj*40;
      vt[jj][c] = Vpack[((size_t)(j0+jj)*12 + h)*40 + c];
    }
    __syncthreads();
    if (tid < 160) {
      #pragma unroll 4
      for (int jj0 = 0; jj0 < 128; jj0 += 4) {
        float4 a4 = *(const float4*)&at[tm][jj0];
        float4 v0 = *(const float4*)&vt[jj0+0][tn*4];
        float4 v1 = *(const float4*)&vt[jj0+1][tn*4];
        float4 v2 = *(const float4*)&vt[jj0+2][tn*4];
        float4 v3 = *(const float4*)&vt[jj0+3][tn*4];
        acc[0] = fmaf(a4.x, v0.x, acc[0]);
        acc[1] = fmaf(a4.x, v0.y, acc[1]);
        acc[2] = fmaf(a4.x, v0.z, acc[2]);
        acc[3] = fmaf(a4.x, v0.w, acc[3]);
        acc[0] = fmaf(a4.y, v1.x, acc[0]);
        acc[1] = fmaf(a4.y, v1.y, acc[1]);
        acc[2] = fmaf(a4.y, v1.z, acc[2]);
        acc[3] = fmaf(a4.y, v1.w, acc[3]);
        acc[0] = fmaf(a4.z, v2.x, acc[0]);
        acc[1] = fmaf(a4.z, v2.y, acc[1]);
        acc[2] = fmaf(a4.z, v2.z, acc[2]);
        acc[3] = fmaf(a4.z, v2.w, acc[3]);
        acc[0] = fmaf(a4.w, v3.x, acc[0]);
        acc[1] = fmaf(a4.w, v3.y, acc[1]);
        acc[2] = fmaf(a4.w, v3.z, acc[2]);
        acc[3] = fmaf(a4.w, v3.w, acc[3]);
      }
    }
    __syncthreads();
  }
  if (tid < 160) {
    const int i = i0 + tm;
    #pragma unroll
    for (int c = 0; c < 4; ++c) {
      int col = tn*4 + c;
      if (col < 16)      feat[(size_t)i*2112 + h*16 + col] = acc[c];
      else               rpt[((size_t)i*NHEAD + h)*24 + (col-16)] = acc[c];
    }
  }
}

// ---------------- point epilogue --------------------------------------------
__global__ __launch_bounds__(256) void pt_epilogue_kernel(
    const float* __restrict__ rpt,
    const float* __restrict__ rot, const float* __restrict__ tra,
    float* __restrict__ feat)
{
  int idx = blockIdx.x * 256 + threadIdx.x;
  if (idx >= N_RES * 96) return;
  int i = idx / 96, m = idx - i*96;
  int h = m >> 3, p = m & 7;
  const float* rp = rpt + ((size_t)i*NHEAD + h)*24 + p;
  float gx = rp[0]  - tra[i];
  float gy = rp[8]  - tra[N_RES + i];
  float gz = rp[16] - tra[2*N_RES + i];
  float lx = rot[0*N_RES+i]*gx + rot[3*N_RES+i]*gy + rot[6*N_RES+i]*gz;
  float ly = rot[1*N_RES+i]*gx + rot[4*N_RES+i]*gy + rot[7*N_RES+i]*gz;
  float lz = rot[2*N_RES+i]*gx + rot[5*N_RES+i]*gy + rot[8*N_RES+i]*gz;
  float dist = sqrtf(1e-8f + lx*lx + ly*ly + lz*lz);
  float* f = feat + (size_t)i*2112 + 192;
  f[m]       = lx;
  f[96 + m]  = ly;
  f[192 + m] = lz;
  f[288 + m] = dist;
}

extern "C" void kernel_launch(void* const* d_in, const int* in_sizes, int n_in,
                              void* d_out, int out_size, void* d_ws, size_t ws_size,
                              hipStream_t stream)
{
  const float* in1d = (const float*)d_in[0];
  const float* in2d = (const float*)d_in[1];
  const float* mask = (const float*)d_in[2];
  const float* rot  = (const float*)d_in[3];
  const float* tra  = (const float*)d_in[4];
  const float* wq   = (const float*)d_in[5];
  const float* bq   = (const float*)d_in[6];
  const float* wkv  = (const float*)d_in[7];
  const float* bkv  = (const float*)d_in[8];
  const float* wqp  = (const float*)d_in[9];
  const float* bqp  = (const float*)d_in[10];
  const float* wkvp = (const float*)d_in[11];
  const float* bkvp = (const float*)d_in[12];
  const float* tpw  = (const float*)d_in[13];
  const float* w2d  = (const float*)d_in[14];
  const float* b2d  = (const float*)d_in[15];
  const float* wout = (const float*)d_in[16];
  const float* bout = (const float*)d_in[17];
  float* out = (float*)d_out;

  float* ws = (float*)d_ws;
  float* Upack    = ws;                  // 294912
  float* Kpack    = ws + 294912;         // 294912  -> 589824
  float* Vpack    = ws + 589824;         // 368640  -> 958464
  float* wT       = ws + 958464;         // 1536    -> 960000
  float* feat     = ws + 960000;         // 1622016 -> 2582016
  float* invS     = ws + 2582016;        // 9216    -> 2591232
  float* rpt      = ws + 2591232;        // 221184  -> 2812416
  // region X at 2812416: proj_all(884736) | B_all(442368) | bias_all(1152)
  float* proj_all = ws + 2812416;        // dead after point_pack
  float* B_all    = ws + 3697152;        // dead after proj GEMM
  float* bias_all = ws + 4139520;        // dead after proj GEMM
  // logits aliases region X (written by logits_sp AFTER point_pack)
  float* logits   = ws + 2812416;        // 7077888 -> 9890304
  float* part     = ws + 2812416;        // 12*294912 = 3538944 <= 7077888 (alias)
  // high-water: 9890304 floats = 39.6 MB

  pack_b_kernel<<<432, 256, 0, stream>>>(wq, wkv, wqp, wkvp, B_all);
  pack_small_kernel<<<11, 256, 0, stream>>>(bq, bkv, bqp, bkvp, w2d, bias_all, wT);
  gemm_kernel<<<dim3(18,12,1), 256, 0, stream>>>(in1d, 384, B_all, 1152, bias_all,
                                                 proj_all, 1152, 768, 384, 384);
  point_pack_kernel<<<36, 256, 0, stream>>>(proj_all, rot, tra, tpw, b2d, mask,
                                            Upack, Kpack, Vpack);
  logits_sp_kernel<<<dim3(12,12,12), 256, 0, stream>>>(Upack, Kpack, logits);
  fused_attn_kernel<<<N_RES, 256, 0, stream>>>(in2d, wT, logits, invS, feat);
  res_sv_pt_kernel<<<dim3(12,48), 256, 0, stream>>>(logits, invS, Vpack, feat, rpt);
  pt_epilogue_kernel<<<288, 256, 0, stream>>>(rpt, rot, tra, feat);
  gemm_kernel<<<dim3(6,12,OUT_SPLIT), 256, 0, stream>>>(feat, 2112, wout, 384, nullptr,
                                                        part, 384, 768, 2112, 176);
  reduce_out_kernel<<<288, 256, 0, stream>>>(part, bout, out);
}

// Round 24
// 251.437 us; speedup vs baseline: 1.3676x; 1.0153x over previous
//
#include <hip/hip_runtime.h>
#include <cstdint>
#include <cstddef>

// InvariantPointAttention N=768, H=12, C=384, PD=128, SQK=SV=16, PQK=4, PV=8.
// Round 24: R23 base (255.3us proven). Parameter-only edit: projection GEMM
// split-K z=2 (216 -> 432 blocks; was 0.84 blocks/CU, worst remaining
// occupancy) + reduce_proj (2 partials + bias). All else frozen.

#define N_RES 768
#define NHEAD 12
#define NN (768*768)
#define OUT_SPLIT 12

__device__ __forceinline__ float softplusf_(float x) {
  return (x > 20.f) ? x : log1pf(__expf(x));
}

// ---------------- pack B_all[384][1152] from 4 weight mats ------------------
__global__ __launch_bounds__(256) void pack_b_kernel(
    const float* __restrict__ wq, const float* __restrict__ wkv,
    const float* __restrict__ wqp, const float* __restrict__ wkvp,
    float* __restrict__ B_all)
{
  int idx4 = blockIdx.x * 256 + threadIdx.x;   // 110592 units
  int k = idx4 / 288;
  int n = (idx4 - k*288) * 4;
  float4 v;
  if (n < 192)       v = *(const float4*)(wq   + (size_t)k*192 + n);
  else if (n < 576)  v = *(const float4*)(wkv  + (size_t)k*384 + (n-192));
  else if (n < 720)  v = *(const float4*)(wqp  + (size_t)k*144 + (n-576));
  else               v = *(const float4*)(wkvp + (size_t)k*432 + (n-720));
  *(float4*)(B_all + (size_t)k*1152 + n) = v;
}

// ---------------- pack bias_all[1152] + wT[12][128] -------------------------
__global__ __launch_bounds__(256) void pack_small_kernel(
    const float* __restrict__ bq, const float* __restrict__ bkv,
    const float* __restrict__ bqp, const float* __restrict__ bkvp,
    const float* __restrict__ w2d,
    float* __restrict__ bias_all, float* __restrict__ wT)
{
  int idx = blockIdx.x * 256 + threadIdx.x;
  if (idx < 1152) {
    float v;
    if (idx < 192)      v = bq[idx];
    else if (idx < 576) v = bkv[idx-192];
    else if (idx < 720) v = bqp[idx-576];
    else                v = bkvp[idx-720];
    bias_all[idx] = v;
  } else if (idx < 2688) {
    int t = idx - 1152;
    int h = t >> 7, c = t & 127;
    wT[h*128 + c] = 0.5773502691896258f * w2d[c*12 + h];
  }
}

// ---------------- tiled GEMM, optional split-K ------------------------------
__global__ __launch_bounds__(256) void gemm_kernel(
    const float* __restrict__ A, int lda,
    const float* __restrict__ B, int ldb,
    const float* __restrict__ bias,
    float* __restrict__ C, int ldc,
    int M, int K, int kPerSplit)
{
  __shared__ float As[16][68];
  __shared__ float Bs[16][68];
  const int tid = threadIdx.x;
  const int m0 = blockIdx.y * 64, n0 = blockIdx.x * 64;
  const int kbeg = blockIdx.z * kPerSplit;
  const int kend = kbeg + kPerSplit;
  const int tn = tid & 15, tm = tid >> 4;
  float acc[4][4] = {};
  for (int k0 = kbeg; k0 < kend; k0 += 16) {
    {
      int idx = tid * 4;
      int m = idx >> 4, kk = idx & 15;
      float4 a = *(const float4*)(A + (size_t)(m0+m)*lda + k0 + kk);
      As[kk+0][m] = a.x; As[kk+1][m] = a.y; As[kk+2][m] = a.z; As[kk+3][m] = a.w;
    }
    {
      int kk = tid >> 4, n = (tid & 15) * 4;
      float4 b = *(const float4*)(B + (size_t)(k0+kk)*ldb + n0 + n);
      *(float4*)&Bs[kk][n] = b;
    }
    __syncthreads();
    #pragma unroll
    for (int k = 0; k < 16; ++k) {
      float4 a = *(const float4*)&As[k][tm*4];
      float4 b = *(const float4*)&Bs[k][tn*4];
      acc[0][0]=fmaf(a.x,b.x,acc[0][0]); acc[0][1]=fmaf(a.x,b.y,acc[0][1]);
      acc[0][2]=fmaf(a.x,b.z,acc[0][2]); acc[0][3]=fmaf(a.x,b.w,acc[0][3]);
      acc[1][0]=fmaf(a.y,b.x,acc[1][0]); acc[1][1]=fmaf(a.y,b.y,acc[1][1]);
      acc[1][2]=fmaf(a.y,b.z,acc[1][2]); acc[1][3]=fmaf(a.y,b.w,acc[1][3]);
      acc[2][0]=fmaf(a.z,b.x,acc[2][0]); acc[2][1]=fmaf(a.z,b.y,acc[2][1]);
      acc[2][2]=fmaf(a.z,b.z,acc[2][2]); acc[2][3]=fmaf(a.z,b.w,acc[2][3]);
      acc[3][0]=fmaf(a.w,b.x,acc[3][0]); acc[3][1]=fmaf(a.w,b.y,acc[3][1]);
      acc[3][2]=fmaf(a.w,b.z,acc[3][2]); acc[3][3]=fmaf(a.w,b.w,acc[3][3]);
    }
    __syncthreads();
  }
  float* Cp = C + (size_t)blockIdx.z * M * ldc;
  if (gridDim.z == 1) {
    #pragma unroll
    for (int r = 0; r < 4; ++r) {
      float* cp = Cp + (size_t)(m0 + tm*4 + r)*ldc + n0 + tn*4;
      #pragma unroll
      for (int c = 0; c < 4; ++c) cp[c] = acc[r][c] + bias[n0 + tn*4 + c];
    }
  } else {
    #pragma unroll
    for (int r = 0; r < 4; ++r) {
      float* cp = Cp + (size_t)(m0 + tm*4 + r)*ldc + n0 + tn*4;
      #pragma unroll
      for (int c = 0; c < 4; ++c) cp[c] = acc[r][c];
    }
  }
}

// ---------------- split-K reduce + bias for the output GEMM (12 partials) ---
__global__ __launch_bounds__(256) void reduce_out_kernel(
    const float* __restrict__ part, const float* __restrict__ bout,
    float* __restrict__ out)
{
  int idx4 = blockIdx.x * 256 + threadIdx.x;   // 73728 units
  if (idx4 >= 73728) return;
  int n4 = idx4 % 96;
  float4 a = *(const float4*)(bout + n4*4);
  #pragma unroll
  for (int z = 0; z < OUT_SPLIT; ++z) {
    float4 p = *(const float4*)(part + (size_t)z*294912 + (size_t)idx4*4);
    a.x += p.x; a.y += p.y; a.z += p.z; a.w += p.w;
  }
  *(float4*)(out + (size_t)idx4*4) = a;
}

// ---------------- split-K reduce + bias for the proj GEMM (2 partials) ------
__global__ __launch_bounds__(256) void reduce_proj_kernel(
    const float* __restrict__ part, const float* __restrict__ bias,
    float* __restrict__ proj)
{
  int idx4 = blockIdx.x * 256 + threadIdx.x;   // 221184 units
  if (idx4 >= 221184) return;
  size_t off = (size_t)idx4 * 4;
  int n = (int)(off % 1152);
  float4 a = *(const float4*)(bias + n);
  float4 p0 = *(const float4*)(part + off);
  float4 p1 = *(const float4*)(part + 884736 + off);
  a.x += p0.x + p1.x;
  a.y += p0.y + p1.y;
  a.z += p0.z + p1.z;
  a.w += p0.w + p1.w;
  *(float4*)(proj + off) = a;
}

// ---------------- build packed U/K/V vectors --------------------------------
// U[h][i][32]: [sw*qs(16), pw*qpt(12), ci, 50*mi, -0.5*pw, 0]
// K[h][j][32]: [ks(16), kpt(12), 1, mj, kn, 0]
// V[j][h][40]: [vs(16), vpt(24, d*8+p)]
__global__ __launch_bounds__(256) void point_pack_kernel(
    const float* __restrict__ proj, const float* __restrict__ rot,
    const float* __restrict__ tra, const float* __restrict__ tpw,
    const float* __restrict__ b2d, const float* __restrict__ mask,
    float* __restrict__ Upack, float* __restrict__ Kpack, float* __restrict__ Vpack)
{
  int idx = blockIdx.x * 256 + threadIdx.x;
  if (idx >= N_RES * NHEAD) return;
  int i = idx / NHEAD, h = idx - i*NHEAD;
  float R[9], T[3];
  #pragma unroll
  for (int r = 0; r < 9; ++r) R[r] = rot[r*N_RES + i];
  #pragma unroll
  for (int d = 0; d < 3; ++d) T[d] = tra[d*N_RES + i];
  const float pw = 0.13608276348795434f * softplusf_(tpw[h]); // sqrt(1/54)*sp
  const float sw = 0.14433756729740643f;                      // sqrt(1/48)
  const float s3 = 0.5773502691896258f;                       // sqrt(1/3)
  const float* prow = proj + (size_t)i * 1152;
  float* U  = Upack + ((size_t)h * N_RES + i) * 32;
  float* Kp = Kpack + ((size_t)h * N_RES + i) * 32;
  float* Vp = Vpack + (size_t)idx * 40;
  #pragma unroll
  for (int c = 0; c < 16; ++c) U[c]  = sw * prow[h*16 + c];
  #pragma unroll
  for (int c = 0; c < 16; ++c) Kp[c] = prow[192 + h*32 + c];
  #pragma unroll
  for (int c = 0; c < 16; ++c) Vp[c] = prow[192 + h*32 + 16 + c];
  float qn = 0.f;
  #pragma unroll
  for (int p = 0; p < 4; ++p) {
    float x = prow[576      + h*4 + p];
    float y = prow[576 + 48 + h*4 + p];
    float z = prow[576 + 96 + h*4 + p];
    #pragma unroll
    for (int d = 0; d < 3; ++d) {
      float v = R[3*d]*x + R[3*d+1]*y + R[3*d+2]*z + T[d];
      U[16 + d*4 + p] = pw * v;
      qn += v*v;
    }
  }
  float kn = 0.f;
  #pragma unroll
  for (int m = 0; m < 12; ++m) {
    float x = prow[720       + h*12 + m];
    float y = prow[720 + 144 + h*12 + m];
    float z = prow[720 + 288 + h*12 + m];
    #pragma unroll
    for (int d = 0; d < 3; ++d) {
      float v = R[3*d]*x + R[3*d+1]*y + R[3*d+2]*z + T[d];
      if (m < 4) { Kp[16 + d*4 + m] = v; kn += v*v; }
      else       { Vp[16 + d*8 + (m-4)] = v; }
    }
  }
  U[28] = -0.5f*pw*qn + s3*b2d[h] - 50.f;  U[29] = 50.f * mask[i];
  U[30] = -0.5f*pw;                        U[31] = 0.f;
  Kp[28] = 1.f;   Kp[29] = mask[i];
  Kp[30] = kn;    Kp[31] = 0.f;
}

// ---------------- scalar+point logits: Lsp[h] = U[h] @ K[h]^T (rank 32) -----
// k-major LDS tiles [32][68]: 2x ds_read_b128 per k (R22 proven).
__global__ __launch_bounds__(256) void logits_sp_kernel(
    const float* __restrict__ Upack, const float* __restrict__ Kpack,
    float* __restrict__ Lsp)
{
  __shared__ __align__(16) float Ut[32][68];
  __shared__ __align__(16) float Kt[32][68];
  const int h = blockIdx.z;
  const int i0 = blockIdx.y * 64, j0 = blockIdx.x * 64;
  const int tid = threadIdx.x;
  for (int t = tid; t < 512; t += 256) {
    int row = t >> 3, c4 = (t & 7) * 4;
    float4 u = *(const float4*)(Upack + ((size_t)h*N_RES + i0 + row)*32 + c4);
    float4 k = *(const float4*)(Kpack + ((size_t)h*N_RES + j0 + row)*32 + c4);
    Ut[c4+0][row] = u.x; Ut[c4+1][row] = u.y; Ut[c4+2][row] = u.z; Ut[c4+3][row] = u.w;
    Kt[c4+0][row] = k.x; Kt[c4+1][row] = k.y; Kt[c4+2][row] = k.z; Kt[c4+3][row] = k.w;
  }
  __syncthreads();
  const int tn = tid & 15, tm = tid >> 4;
  float acc[4][4] = {};
  #pragma unroll
  for (int k = 0; k < 32; ++k) {
    float4 a = *(const float4*)&Ut[k][tm*4];
    float4 b = *(const float4*)&Kt[k][tn*4];
    acc[0][0]=fmaf(a.x,b.x,acc[0][0]); acc[0][1]=fmaf(a.x,b.y,acc[0][1]);
    acc[0][2]=fmaf(a.x,b.z,acc[0][2]); acc[0][3]=fmaf(a.x,b.w,acc[0][3]);
    acc[1][0]=fmaf(a.y,b.x,acc[1][0]); acc[1][1]=fmaf(a.y,b.y,acc[1][1]);
    acc[1][2]=fmaf(a.y,b.z,acc[1][2]); acc[1][3]=fmaf(a.y,b.w,acc[1][3]);
    acc[2][0]=fmaf(a.z,b.x,acc[2][0]); acc[2][1]=fmaf(a.z,b.y,acc[2][1]);
    acc[2][2]=fmaf(a.z,b.z,acc[2][2]); acc[2][3]=fmaf(a.z,b.w,acc[2][3]);
    acc[3][0]=fmaf(a.w,b.x,acc[3][0]); acc[3][1]=fmaf(a.w,b.y,acc[3][1]);
    acc[3][2]=fmaf(a.w,b.z,acc[3][2]); acc[3][3]=fmaf(a.w,b.w,acc[3][3]);
  }
  #pragma unroll
  for (int r = 0; r < 4; ++r) {
    float4 v = make_float4(acc[r][0], acc[r][1], acc[r][2], acc[r][3]);
    *(float4*)(Lsp + (size_t)h*NN + (size_t)(i0 + tm*4 + r)*N_RES + j0 + tn*4) = v;
  }
}

// ---------------- fused: coalesced att2d + exp + res2d (R16 VERBATIM) -------
__global__ __launch_bounds__(256) void fused_attn_kernel(
    const float* __restrict__ in2d, const float* __restrict__ wT,
    float* __restrict__ logits,     // in: Lsp, out: P = exp(logit) (in-place)
    float* __restrict__ invS, float* __restrict__ feat)
{
  __shared__ __align__(16) float wTs[12][128];   // 6 KB
  __shared__ __align__(16) float Pt[128][12];    // 6 KB
  __shared__ float comb[12][128];                // 6 KB
  __shared__ float inv_sh[12];
  const int i = blockIdx.x;
  const int tid = threadIdx.x;
  const int wave = tid >> 6, lane = tid & 63;
  const int h0 = wave * 3;
  const int g = lane >> 2, t = lane & 3;
  for (int u = tid; u < 1536; u += 256) wTs[u >> 7][u & 127] = wT[u];
  __syncthreads();
  float s_run = 0.f;                 // head h0+t (t<3); t==3 unused
  const int oc = tid & 127, ohalf = tid >> 7;
  float oacc[12];
  #pragma unroll
  for (int h = 0; h < 12; ++h) oacc[h] = 0.f;

  for (int jt = 0; jt < 6; ++jt) {
    const int j0 = jt * 128;
    // ---- att2d + logits + exp: 8 rounds x 16 j ----
    #pragma unroll 2
    for (int r8 = 0; r8 < 8; ++r8) {
      const int j = j0 + r8*16 + g;
      const float* xrow = in2d + ((size_t)i*N_RES + j) * 128;
      float t0 = 0.f, t1 = 0.f, t2 = 0.f;
      #pragma unroll
      for (int c = 0; c < 8; ++c) {
        const int ch = c*16 + t*4;
        float4 x  = *(const float4*)(xrow + ch);
        float4 wa = *(const float4*)&wTs[h0+0][ch];
        float4 wb = *(const float4*)&wTs[h0+1][ch];
        float4 wc = *(const float4*)&wTs[h0+2][ch];
        t0 = fmaf(x.x,wa.x, fmaf(x.y,wa.y, fmaf(x.z,wa.z, fmaf(x.w,wa.w, t0))));
        t1 = fmaf(x.x,wb.x, fmaf(x.y,wb.y, fmaf(x.z,wb.z, fmaf(x.w,wb.w, t1))));
        t2 = fmaf(x.x,wc.x, fmaf(x.y,wc.y, fmaf(x.z,wc.z, fmaf(x.w,wc.w, t2))));
      }
      // butterfly over the 4-lane group
      t0 += __shfl_xor(t0, 1); t0 += __shfl_xor(t0, 2);
      t1 += __shfl_xor(t1, 1); t1 += __shfl_xor(t1, 2);
      t2 += __shfl_xor(t2, 1); t2 += __shfl_xor(t2, 2);
      if (t < 3) {
        float td = (t == 0) ? t0 : ((t == 1) ? t1 : t2);
        const size_t off = (size_t)(h0+t)*NN + (size_t)i*N_RES + j;
        float l = logits[off] + td;
        float p = __expf(l);
        logits[off] = p;              // store P in place
        s_run += p;
        Pt[r8*16 + g][h0 + t] = p;
      }
    }
    __syncthreads();
    // ---- res2d: 128 rows, thread handles rows [ohalf*64, +64), channel oc --
    {
      const float* xb = in2d + ((size_t)i*N_RES + j0 + ohalf*64) * 128 + oc;
      #pragma unroll 4
      for (int jj = 0; jj < 64; ++jj) {
        int row = ohalf*64 + jj;
        float x = xb[(size_t)jj * 128];
        float4 p0 = *(const float4*)&Pt[row][0];
        float4 p1 = *(const float4*)&Pt[row][4];
        float4 p2 = *(const float4*)&Pt[row][8];
        oacc[0] = fmaf(p0.x, x, oacc[0]);
        oacc[1] = fmaf(p0.y, x, oacc[1]);
        oacc[2] = fmaf(p0.z, x, oacc[2]);
        oacc[3] = fmaf(p0.w, x, oacc[3]);
        oacc[4] = fmaf(p1.x, x, oacc[4]);
        oacc[5] = fmaf(p1.y, x, oacc[5]);
        oacc[6] = fmaf(p1.z, x, oacc[6]);
        oacc[7] = fmaf(p1.w, x, oacc[7]);
        oacc[8] = fmaf(p2.x, x, oacc[8]);
        oacc[9] = fmaf(p2.y, x, oacc[9]);
        oacc[10] = fmaf(p2.z, x, oacc[10]);
        oacc[11] = fmaf(p2.w, x, oacc[11]);
      }
    }
    __syncthreads();   // Pt consumed; safe to overwrite next iter
  }
  // ---- denominators: butterfly over g-bits (4,8,16,32), lanes 0..2 write ---
  {
    float s = s_run;
    s += __shfl_xor(s, 4);
    s += __shfl_xor(s, 8);
    s += __shfl_xor(s, 16);
    s += __shfl_xor(s, 32);
    if (g == 0 && t < 3) {
      float inv = 1.f / s;
      inv_sh[h0 + t] = inv;
      invS[(size_t)i*12 + h0 + t] = inv;
    }
  }
  if (ohalf == 1) {
    #pragma unroll
    for (int h = 0; h < 12; ++h) comb[h][oc] = oacc[h];
  }
  __syncthreads();
  if (ohalf == 0) {
    float* f = feat + (size_t)i*2112 + 576;
    #pragma unroll
    for (int h = 0; h < 12; ++h)
      f[h*128 + oc] = (oacc[h] + comb[h][oc]) * inv_sh[h];
  }
}

// ---------------- attn @ [vs | v_pt] per head -- b128 LDS reads -------------
__global__ __launch_bounds__(256) void res_sv_pt_kernel(
    const float* __restrict__ Pbuf, const float* __restrict__ invS,
    const float* __restrict__ Vpack, float* __restrict__ feat,
    float* __restrict__ rpt)
{
  __shared__ __align__(16) float at[16][132];
  __shared__ __align__(16) float vt[128][44];
  const int h = blockIdx.x;
  const int i0 = blockIdx.y * 16;
  const int tid = threadIdx.x;
  const int tm = tid / 10, tn = tid - tm*10;   // valid when tid < 160
  float acc[4] = {};
  for (int j0 = 0; j0 < 768; j0 += 128) {
    for (int t = tid; t < 16*32; t += 256) {
      int ii = t >> 5, jf = t & 31;
      float4 v = *(const float4*)(Pbuf + (size_t)h*NN + (size_t)(i0+ii)*N_RES + j0 + jf*4);
      float inv = invS[(size_t)(i0+ii)*12 + h];
      at[ii][jf*4+0] = v.x * inv;
      at[ii][jf*4+1] = v.y * inv;
      at[ii][jf*4+2] = v.z * inv;
      at[ii][jf*4+3] = v.w * inv;
    }
    for (int t = tid; t < 128*40; t += 256) {
      int jj = t / 40, c = t - jj*40;
      vt[jj][c] = Vpack[((size_t)(j0+jj)*12 + h)*40 + c];
    }
    __syncthreads();
    if (tid < 160) {
      #pragma unroll 4
      for (int jj0 = 0; jj0 < 128; jj0 += 4) {
        float4 a4 = *(const float4*)&at[tm][jj0];
        float4 v0 = *(const float4*)&vt[jj0+0][tn*4];
        float4 v1 = *(const float4*)&vt[jj0+1][tn*4];
        float4 v2 = *(const float4*)&vt[jj0+2][tn*4];
        float4 v3 = *(const float4*)&vt[jj0+3][tn*4];
        acc[0] = fmaf(a4.x, v0.x, acc[0]);
        acc[1] = fmaf(a4.x, v0.y, acc[1]);
        acc[2] = fmaf(a4.x, v0.z, acc[2]);
        acc[3] = fmaf(a4.x, v0.w, acc[3]);
        acc[0] = fmaf(a4.y, v1.x, acc[0]);
        acc[1] = fmaf(a4.y, v1.y, acc[1]);
        acc[2] = fmaf(a4.y, v1.z, acc[2]);
        acc[3] = fmaf(a4.y, v1.w, acc[3]);
        acc[0] = fmaf(a4.z, v2.x, acc[0]);
        acc[1] = fmaf(a4.z, v2.y, acc[1]);
        acc[2] = fmaf(a4.z, v2.z, acc[2]);
        acc[3] = fmaf(a4.z, v2.w, acc[3]);
        acc[0] = fmaf(a4.w, v3.x, acc[0]);
        acc[1] = fmaf(a4.w, v3.y, acc[1]);
        acc[2] = fmaf(a4.w, v3.z, acc[2]);
        acc[3] = fmaf(a4.w, v3.w, acc[3]);
      }
    }
    __syncthreads();
  }
  if (tid < 160) {
    const int i = i0 + tm;
    #pragma unroll
    for (int c = 0; c < 4; ++c) {
      int col = tn*4 + c;
      if (col < 16)      feat[(size_t)i*2112 + h*16 + col] = acc[c];
      else               rpt[((size_t)i*NHEAD + h)*24 + (col-16)] = acc[c];
    }
  }
}

// ---------------- point epilogue --------------------------------------------
__global__ __launch_bounds__(256) void pt_epilogue_kernel(
    const float* __restrict__ rpt,
    const float* __restrict__ rot, const float* __restrict__ tra,
    float* __restrict__ feat)
{
  int idx = blockIdx.x * 256 + threadIdx.x;
  if (idx >= N_RES * 96) return;
  int i = idx / 96, m = idx - i*96;
  int h = m >> 3, p = m & 7;
  const float* rp = rpt + ((size_t)i*NHEAD + h)*24 + p;
  float gx = rp[0]  - tra[i];
  float gy = rp[8]  - tra[N_RES + i];
  float gz = rp[16] - tra[2*N_RES + i];
  float lx = rot[0*N_RES+i]*gx + rot[3*N_RES+i]*gy + rot[6*N_RES+i]*gz;
  float ly = rot[1*N_RES+i]*gx + rot[4*N_RES+i]*gy + rot[7*N_RES+i]*gz;
  float lz = rot[2*N_RES+i]*gx + rot[5*N_RES+i]*gy + rot[8*N_RES+i]*gz;
  float dist = sqrtf(1e-8f + lx*lx + ly*ly + lz*lz);
  float* f = feat + (size_t)i*2112 + 192;
  f[m]       = lx;
  f[96 + m]  = ly;
  f[192 + m] = lz;
  f[288 + m] = dist;
}

extern "C" void kernel_launch(void* const* d_in, const int* in_sizes, int n_in,
                              void* d_out, int out_size, void* d_ws, size_t ws_size,
                              hipStream_t stream)
{
  const float* in1d = (const float*)d_in[0];
  const float* in2d = (const float*)d_in[1];
  const float* mask = (const float*)d_in[2];
  const float* rot  = (const float*)d_in[3];
  const float* tra  = (const float*)d_in[4];
  const float* wq   = (const float*)d_in[5];
  const float* bq   = (const float*)d_in[6];
  const float* wkv  = (const float*)d_in[7];
  const float* bkv  = (const float*)d_in[8];
  const float* wqp  = (const float*)d_in[9];
  const float* bqp  = (const float*)d_in[10];
  const float* wkvp = (const float*)d_in[11];
  const float* bkvp = (const float*)d_in[12];
  const float* tpw  = (const float*)d_in[13];
  const float* w2d  = (const float*)d_in[14];
  const float* b2d  = (const float*)d_in[15];
  const float* wout = (const float*)d_in[16];
  const float* bout = (const float*)d_in[17];
  float* out = (float*)d_out;

  float* ws = (float*)d_ws;
  float* Upack    = ws;                  // 294912
  float* Kpack    = ws + 294912;         // 294912  -> 589824
  float* Vpack    = ws + 589824;         // 368640  -> 958464
  float* wT       = ws + 958464;         // 1536    -> 960000
  float* feat     = ws + 960000;         // 1622016 -> 2582016
  float* invS     = ws + 2582016;        // 9216    -> 2591232
  float* rpt      = ws + 2591232;        // 221184  -> 2812416
  // region X at 2812416: proj_all(884736) | B_all(442368) | bias_all(1152) |
  //                      part_proj(1769472, ends 5910144)
  float* proj_all = ws + 2812416;        // dead after point_pack
  float* B_all    = ws + 3697152;        // dead after proj reduce
  float* bias_all = ws + 4139520;        // dead after proj reduce
  float* part_proj= ws + 4140672;        // 2*884736 (dead after proj reduce)
  // logits aliases region X (written by logits_sp AFTER point_pack)
  float* logits   = ws + 2812416;        // 7077888 -> 9890304
  float* part     = ws + 2812416;        // 12*294912 = 3538944 <= 7077888 (alias)
  // high-water: 9890304 floats = 39.6 MB

  pack_b_kernel<<<432, 256, 0, stream>>>(wq, wkv, wqp, wkvp, B_all);
  pack_small_kernel<<<11, 256, 0, stream>>>(bq, bkv, bqp, bkvp, w2d, bias_all, wT);
  // projection GEMM, split-K z=2 into part_proj, then reduce+bias
  gemm_kernel<<<dim3(18,12,2), 256, 0, stream>>>(in1d, 384, B_all, 1152, nullptr,
                                                 part_proj, 1152, 768, 384, 192);
  reduce_proj_kernel<<<864, 256, 0, stream>>>(part_proj, bias_all, proj_all);
  point_pack_kernel<<<36, 256, 0, stream>>>(proj_all, rot, tra, tpw, b2d, mask,
                                            Upack, Kpack, Vpack);
  logits_sp_kernel<<<dim3(12,12,12), 256, 0, stream>>>(Upack, Kpack, logits);
  fused_attn_kernel<<<N_RES, 256, 0, stream>>>(in2d, wT, logits, invS, feat);
  res_sv_pt_kernel<<<dim3(12,48), 256, 0, stream>>>(logits, invS, Vpack, feat, rpt);
  pt_epilogue_kernel<<<288, 256, 0, stream>>>(rpt, rot, tra, feat);
  gemm_kernel<<<dim3(6,12,OUT_SPLIT), 256, 0, stream>>>(feat, 2112, wout, 384, nullptr,
                                                        part, 384, 768, 2112, 176);
  reduce_out_kernel<<<288, 256, 0, stream>>>(part, bout, out);
}

// Round 25
// 246.761 us; speedup vs baseline: 1.3935x; 1.0189x over previous
//
#include <hip/hip_runtime.h>
#include <cstdint>
#include <cstddef>

// InvariantPointAttention N=768, H=12, C=384, PD=128, SQK=SV=16, PQK=4, PV=8.
// Round 25: R24 base (251.4us proven). Same proven split recipe applied to
// res_sv_pt: j-split z=2 (576 -> 1152 blocks), float4 partials to pav above
// the logits high-water, reduce_sv sums 2 partials into feat/rpt. All else
// frozen (fused = R16, logits_sp = R22, GEMM splits = R23/R24).

#define N_RES 768
#define NHEAD 12
#define NN (768*768)
#define OUT_SPLIT 12

__device__ __forceinline__ float softplusf_(float x) {
  return (x > 20.f) ? x : log1pf(__expf(x));
}

// ---------------- pack B_all[384][1152] from 4 weight mats ------------------
__global__ __launch_bounds__(256) void pack_b_kernel(
    const float* __restrict__ wq, const float* __restrict__ wkv,
    const float* __restrict__ wqp, const float* __restrict__ wkvp,
    float* __restrict__ B_all)
{
  int idx4 = blockIdx.x * 256 + threadIdx.x;   // 110592 units
  int k = idx4 / 288;
  int n = (idx4 - k*288) * 4;
  float4 v;
  if (n < 192)       v = *(const float4*)(wq   + (size_t)k*192 + n);
  else if (n < 576)  v = *(const float4*)(wkv  + (size_t)k*384 + (n-192));
  else if (n < 720)  v = *(const float4*)(wqp  + (size_t)k*144 + (n-576));
  else               v = *(const float4*)(wkvp + (size_t)k*432 + (n-720));
  *(float4*)(B_all + (size_t)k*1152 + n) = v;
}

// ---------------- pack bias_all[1152] + wT[12][128] -------------------------
__global__ __launch_bounds__(256) void pack_small_kernel(
    const float* __restrict__ bq, const float* __restrict__ bkv,
    const float* __restrict__ bqp, const float* __restrict__ bkvp,
    const float* __restrict__ w2d,
    float* __restrict__ bias_all, float* __restrict__ wT)
{
  int idx = blockIdx.x * 256 + threadIdx.x;
  if (idx < 1152) {
    float v;
    if (idx < 192)      v = bq[idx];
    else if (idx < 576) v = bkv[idx-192];
    else if (idx < 720) v = bqp[idx-576];
    else                v = bkvp[idx-720];
    bias_all[idx] = v;
  } else if (idx < 2688) {
    int t = idx - 1152;
    int h = t >> 7, c = t & 127;
    wT[h*128 + c] = 0.5773502691896258f * w2d[c*12 + h];
  }
}

// ---------------- tiled GEMM, optional split-K ------------------------------
__global__ __launch_bounds__(256) void gemm_kernel(
    const float* __restrict__ A, int lda,
    const float* __restrict__ B, int ldb,
    const float* __restrict__ bias,
    float* __restrict__ C, int ldc,
    int M, int K, int kPerSplit)
{
  __shared__ float As[16][68];
  __shared__ float Bs[16][68];
  const int tid = threadIdx.x;
  const int m0 = blockIdx.y * 64, n0 = blockIdx.x * 64;
  const int kbeg = blockIdx.z * kPerSplit;
  const int kend = kbeg + kPerSplit;
  const int tn = tid & 15, tm = tid >> 4;
  float acc[4][4] = {};
  for (int k0 = kbeg; k0 < kend; k0 += 16) {
    {
      int idx = tid * 4;
      int m = idx >> 4, kk = idx & 15;
      float4 a = *(const float4*)(A + (size_t)(m0+m)*lda + k0 + kk);
      As[kk+0][m] = a.x; As[kk+1][m] = a.y; As[kk+2][m] = a.z; As[kk+3][m] = a.w;
    }
    {
      int kk = tid >> 4, n = (tid & 15) * 4;
      float4 b = *(const float4*)(B + (size_t)(k0+kk)*ldb + n0 + n);
      *(float4*)&Bs[kk][n] = b;
    }
    __syncthreads();
    #pragma unroll
    for (int k = 0; k < 16; ++k) {
      float4 a = *(const float4*)&As[k][tm*4];
      float4 b = *(const float4*)&Bs[k][tn*4];
      acc[0][0]=fmaf(a.x,b.x,acc[0][0]); acc[0][1]=fmaf(a.x,b.y,acc[0][1]);
      acc[0][2]=fmaf(a.x,b.z,acc[0][2]); acc[0][3]=fmaf(a.x,b.w,acc[0][3]);
      acc[1][0]=fmaf(a.y,b.x,acc[1][0]); acc[1][1]=fmaf(a.y,b.y,acc[1][1]);
      acc[1][2]=fmaf(a.y,b.z,acc[1][2]); acc[1][3]=fmaf(a.y,b.w,acc[1][3]);
      acc[2][0]=fmaf(a.z,b.x,acc[2][0]); acc[2][1]=fmaf(a.z,b.y,acc[2][1]);
      acc[2][2]=fmaf(a.z,b.z,acc[2][2]); acc[2][3]=fmaf(a.z,b.w,acc[2][3]);
      acc[3][0]=fmaf(a.w,b.x,acc[3][0]); acc[3][1]=fmaf(a.w,b.y,acc[3][1]);
      acc[3][2]=fmaf(a.w,b.z,acc[3][2]); acc[3][3]=fmaf(a.w,b.w,acc[3][3]);
    }
    __syncthreads();
  }
  float* Cp = C + (size_t)blockIdx.z * M * ldc;
  if (gridDim.z == 1) {
    #pragma unroll
    for (int r = 0; r < 4; ++r) {
      float* cp = Cp + (size_t)(m0 + tm*4 + r)*ldc + n0 + tn*4;
      #pragma unroll
      for (int c = 0; c < 4; ++c) cp[c] = acc[r][c] + bias[n0 + tn*4 + c];
    }
  } else {
    #pragma unroll
    for (int r = 0; r < 4; ++r) {
      float* cp = Cp + (size_t)(m0 + tm*4 + r)*ldc + n0 + tn*4;
      #pragma unroll
      for (int c = 0; c < 4; ++c) cp[c] = acc[r][c];
    }
  }
}

// ---------------- split-K reduce + bias for the output GEMM (12 partials) ---
__global__ __launch_bounds__(256) void reduce_out_kernel(
    const float* __restrict__ part, const float* __restrict__ bout,
    float* __restrict__ out)
{
  int idx4 = blockIdx.x * 256 + threadIdx.x;   // 73728 units
  if (idx4 >= 73728) return;
  int n4 = idx4 % 96;
  float4 a = *(const float4*)(bout + n4*4);
  #pragma unroll
  for (int z = 0; z < OUT_SPLIT; ++z) {
    float4 p = *(const float4*)(part + (size_t)z*294912 + (size_t)idx4*4);
    a.x += p.x; a.y += p.y; a.z += p.z; a.w += p.w;
  }
  *(float4*)(out + (size_t)idx4*4) = a;
}

// ---------------- split-K reduce + bias for the proj GEMM (2 partials) ------
__global__ __launch_bounds__(256) void reduce_proj_kernel(
    const float* __restrict__ part, const float* __restrict__ bias,
    float* __restrict__ proj)
{
  int idx4 = blockIdx.x * 256 + threadIdx.x;   // 221184 units
  if (idx4 >= 221184) return;
  size_t off = (size_t)idx4 * 4;
  int n = (int)(off % 1152);
  float4 a = *(const float4*)(bias + n);
  float4 p0 = *(const float4*)(part + off);
  float4 p1 = *(const float4*)(part + 884736 + off);
  a.x += p0.x + p1.x;
  a.y += p0.y + p1.y;
  a.z += p0.z + p1.z;
  a.w += p0.w + p1.w;
  *(float4*)(proj + off) = a;
}

// ---------------- reduce_sv: sum 2 j-partials into feat/rpt -----------------
__global__ __launch_bounds__(256) void reduce_sv_kernel(
    const float* __restrict__ pav, float* __restrict__ feat,
    float* __restrict__ rpt)
{
  int idx4 = blockIdx.x * 256 + threadIdx.x;   // 92160 float4 units
  if (idx4 >= 92160) return;
  int col4 = idx4 % 10;
  int rest = idx4 / 10;
  int i = rest % 768;
  int h = rest / 768;
  size_t o0 = ((size_t)h*768 + i)*40 + col4*4;
  size_t o1 = ((size_t)(12 + h)*768 + i)*40 + col4*4;
  float4 p0 = *(const float4*)(pav + o0);
  float4 p1 = *(const float4*)(pav + o1);
  float4 a = make_float4(p0.x + p1.x, p0.y + p1.y, p0.z + p1.z, p0.w + p1.w);
  int col = col4 * 4;
  if (col < 16) {
    *(float4*)(feat + (size_t)i*2112 + h*16 + col) = a;
  } else {
    *(float4*)(rpt + ((size_t)i*NHEAD + h)*24 + (col - 16)) = a;
  }
}

// ---------------- build packed U/K/V vectors --------------------------------
// U[h][i][32]: [sw*qs(16), pw*qpt(12), ci, 50*mi, -0.5*pw, 0]
// K[h][j][32]: [ks(16), kpt(12), 1, mj, kn, 0]
// V[j][h][40]: [vs(16), vpt(24, d*8+p)]
__global__ __launch_bounds__(256) void point_pack_kernel(
    const float* __restrict__ proj, const float* __restrict__ rot,
    const float* __restrict__ tra, const float* __restrict__ tpw,
    const float* __restrict__ b2d, const float* __restrict__ mask,
    float* __restrict__ Upack, float* __restrict__ Kpack, float* __restrict__ Vpack)
{
  int idx = blockIdx.x * 256 + threadIdx.x;
  if (idx >= N_RES * NHEAD) return;
  int i = idx / NHEAD, h = idx - i*NHEAD;
  float R[9], T[3];
  #pragma unroll
  for (int r = 0; r < 9; ++r) R[r] = rot[r*N_RES + i];
  #pragma unroll
  for (int d = 0; d < 3; ++d) T[d] = tra[d*N_RES + i];
  const float pw = 0.13608276348795434f * softplusf_(tpw[h]); // sqrt(1/54)*sp
  const float sw = 0.14433756729740643f;                      // sqrt(1/48)
  const float s3 = 0.5773502691896258f;                       // sqrt(1/3)
  const float* prow = proj + (size_t)i * 1152;
  float* U  = Upack + ((size_t)h * N_RES + i) * 32;
  float* Kp = Kpack + ((size_t)h * N_RES + i) * 32;
  float* Vp = Vpack + (size_t)idx * 40;
  #pragma unroll
  for (int c = 0; c < 16; ++c) U[c]  = sw * prow[h*16 + c];
  #pragma unroll
  for (int c = 0; c < 16; ++c) Kp[c] = prow[192 + h*32 + c];
  #pragma unroll
  for (int c = 0; c < 16; ++c) Vp[c] = prow[192 + h*32 + 16 + c];
  float qn = 0.f;
  #pragma unroll
  for (int p = 0; p < 4; ++p) {
    float x = prow[576      + h*4 + p];
    float y = prow[576 + 48 + h*4 + p];
    float z = prow[576 + 96 + h*4 + p];
    #pragma unroll
    for (int d = 0; d < 3; ++d) {
      float v = R[3*d]*x + R[3*d+1]*y + R[3*d+2]*z + T[d];
      U[16 + d*4 + p] = pw * v;
      qn += v*v;
    }
  }
  float kn = 0.f;
  #pragma unroll
  for (int m = 0; m < 12; ++m) {
    float x = prow[720       + h*12 + m];
    float y = prow[720 + 144 + h*12 + m];
    float z = prow[720 + 288 + h*12 + m];
    #pragma unroll
    for (int d = 0; d < 3; ++d) {
      float v = R[3*d]*x + R[3*d+1]*y + R[3*d+2]*z + T[d];
      if (m < 4) { Kp[16 + d*4 + m] = v; kn += v*v; }
      else       { Vp[16 + d*8 + (m-4)] = v; }
    }
  }
  U[28] = -0.5f*pw*qn + s3*b2d[h] - 50.f;  U[29] = 50.f * mask[i];
  U[30] = -0.5f*pw;                        U[31] = 0.f;
  Kp[28] = 1.f;   Kp[29] = mask[i];
  Kp[30] = kn;    Kp[31] = 0.f;
}

// ---------------- scalar+point logits: Lsp[h] = U[h] @ K[h]^T (rank 32) -----
// k-major LDS tiles [32][68]: 2x ds_read_b128 per k (R22 proven).
__global__ __launch_bounds__(256) void logits_sp_kernel(
    const float* __restrict__ Upack, const float* __restrict__ Kpack,
    float* __restrict__ Lsp)
{
  __shared__ __align__(16) float Ut[32][68];
  __shared__ __align__(16) float Kt[32][68];
  const int h = blockIdx.z;
  const int i0 = blockIdx.y * 64, j0 = blockIdx.x * 64;
  const int tid = threadIdx.x;
  for (int t = tid; t < 512; t += 256) {
    int row = t >> 3, c4 = (t & 7) * 4;
    float4 u = *(const float4*)(Upack + ((size_t)h*N_RES + i0 + row)*32 + c4);
    float4 k = *(const float4*)(Kpack + ((size_t)h*N_RES + j0 + row)*32 + c4);
    Ut[c4+0][row] = u.x; Ut[c4+1][row] = u.y; Ut[c4+2][row] = u.z; Ut[c4+3][row] = u.w;
    Kt[c4+0][row] = k.x; Kt[c4+1][row] = k.y; Kt[c4+2][row] = k.z; Kt[c4+3][row] = k.w;
  }
  __syncthreads();
  const int tn = tid & 15, tm = tid >> 4;
  float acc[4][4] = {};
  #pragma unroll
  for (int k = 0; k < 32; ++k) {
    float4 a = *(const float4*)&Ut[k][tm*4];
    float4 b = *(const float4*)&Kt[k][tn*4];
    acc[0][0]=fmaf(a.x,b.x,acc[0][0]); acc[0][1]=fmaf(a.x,b.y,acc[0][1]);
    acc[0][2]=fmaf(a.x,b.z,acc[0][2]); acc[0][3]=fmaf(a.x,b.w,acc[0][3]);
    acc[1][0]=fmaf(a.y,b.x,acc[1][0]); acc[1][1]=fmaf(a.y,b.y,acc[1][1]);
    acc[1][2]=fmaf(a.y,b.z,acc[1][2]); acc[1][3]=fmaf(a.y,b.w,acc[1][3]);
    acc[2][0]=fmaf(a.z,b.x,acc[2][0]); acc[2][1]=fmaf(a.z,b.y,acc[2][1]);
    acc[2][2]=fmaf(a.z,b.z,acc[2][2]); acc[2][3]=fmaf(a.z,b.w,acc[2][3]);
    acc[3][0]=fmaf(a.w,b.x,acc[3][0]); acc[3][1]=fmaf(a.w,b.y,acc[3][1]);
    acc[3][2]=fmaf(a.w,b.z,acc[3][2]); acc[3][3]=fmaf(a.w,b.w,acc[3][3]);
  }
  #pragma unroll
  for (int r = 0; r < 4; ++r) {
    float4 v = make_float4(acc[r][0], acc[r][1], acc[r][2], acc[r][3]);
    *(float4*)(Lsp + (size_t)h*NN + (size_t)(i0 + tm*4 + r)*N_RES + j0 + tn*4) = v;
  }
}

// ---------------- fused: coalesced att2d + exp + res2d (R16 VERBATIM) -------
__global__ __launch_bounds__(256) void fused_attn_kernel(
    const float* __restrict__ in2d, const float* __restrict__ wT,
    float* __restrict__ logits,     // in: Lsp, out: P = exp(logit) (in-place)
    float* __restrict__ invS, float* __restrict__ feat)
{
  __shared__ __align__(16) float wTs[12][128];   // 6 KB
  __shared__ __align__(16) float Pt[128][12];    // 6 KB
  __shared__ float comb[12][128];                // 6 KB
  __shared__ float inv_sh[12];
  const int i = blockIdx.x;
  const int tid = threadIdx.x;
  const int wave = tid >> 6, lane = tid & 63;
  const int h0 = wave * 3;
  const int g = lane >> 2, t = lane & 3;
  for (int u = tid; u < 1536; u += 256) wTs[u >> 7][u & 127] = wT[u];
  __syncthreads();
  float s_run = 0.f;                 // head h0+t (t<3); t==3 unused
  const int oc = tid & 127, ohalf = tid >> 7;
  float oacc[12];
  #pragma unroll
  for (int h = 0; h < 12; ++h) oacc[h] = 0.f;

  for (int jt = 0; jt < 6; ++jt) {
    const int j0 = jt * 128;
    // ---- att2d + logits + exp: 8 rounds x 16 j ----
    #pragma unroll 2
    for (int r8 = 0; r8 < 8; ++r8) {
      const int j = j0 + r8*16 + g;
      const float* xrow = in2d + ((size_t)i*N_RES + j) * 128;
      float t0 = 0.f, t1 = 0.f, t2 = 0.f;
      #pragma unroll
      for (int c = 0; c < 8; ++c) {
        const int ch = c*16 + t*4;
        float4 x  = *(const float4*)(xrow + ch);
        float4 wa = *(const float4*)&wTs[h0+0][ch];
        float4 wb = *(const float4*)&wTs[h0+1][ch];
        float4 wc = *(const float4*)&wTs[h0+2][ch];
        t0 = fmaf(x.x,wa.x, fmaf(x.y,wa.y, fmaf(x.z,wa.z, fmaf(x.w,wa.w, t0))));
        t1 = fmaf(x.x,wb.x, fmaf(x.y,wb.y, fmaf(x.z,wb.z, fmaf(x.w,wb.w, t1))));
        t2 = fmaf(x.x,wc.x, fmaf(x.y,wc.y, fmaf(x.z,wc.z, fmaf(x.w,wc.w, t2))));
      }
      // butterfly over the 4-lane group
      t0 += __shfl_xor(t0, 1); t0 += __shfl_xor(t0, 2);
      t1 += __shfl_xor(t1, 1); t1 += __shfl_xor(t1, 2);
      t2 += __shfl_xor(t2, 1); t2 += __shfl_xor(t2, 2);
      if (t < 3) {
        float td = (t == 0) ? t0 : ((t == 1) ? t1 : t2);
        const size_t off = (size_t)(h0+t)*NN + (size_t)i*N_RES + j;
        float l = logits[off] + td;
        float p = __expf(l);
        logits[off] = p;              // store P in place
        s_run += p;
        Pt[r8*16 + g][h0 + t] = p;
      }
    }
    __syncthreads();
    // ---- res2d: 128 rows, thread handles rows [ohalf*64, +64), channel oc --
    {
      const float* xb = in2d + ((size_t)i*N_RES + j0 + ohalf*64) * 128 + oc;
      #pragma unroll 4
      for (int jj = 0; jj < 64; ++jj) {
        int row = ohalf*64 + jj;
        float x = xb[(size_t)jj * 128];
        float4 p0 = *(const float4*)&Pt[row][0];
        float4 p1 = *(const float4*)&Pt[row][4];
        float4 p2 = *(const float4*)&Pt[row][8];
        oacc[0] = fmaf(p0.x, x, oacc[0]);
        oacc[1] = fmaf(p0.y, x, oacc[1]);
        oacc[2] = fmaf(p0.z, x, oacc[2]);
        oacc[3] = fmaf(p0.w, x, oacc[3]);
        oacc[4] = fmaf(p1.x, x, oacc[4]);
        oacc[5] = fmaf(p1.y, x, oacc[5]);
        oacc[6] = fmaf(p1.z, x, oacc[6]);
        oacc[7] = fmaf(p1.w, x, oacc[7]);
        oacc[8] = fmaf(p2.x, x, oacc[8]);
        oacc[9] = fmaf(p2.y, x, oacc[9]);
        oacc[10] = fmaf(p2.z, x, oacc[10]);
        oacc[11] = fmaf(p2.w, x, oacc[11]);
      }
    }
    __syncthreads();   // Pt consumed; safe to overwrite next iter
  }
  // ---- denominators: butterfly over g-bits (4,8,16,32), lanes 0..2 write ---
  {
    float s = s_run;
    s += __shfl_xor(s, 4);
    s += __shfl_xor(s, 8);
    s += __shfl_xor(s, 16);
    s += __shfl_xor(s, 32);
    if (g == 0 && t < 3) {
      float inv = 1.f / s;
      inv_sh[h0 + t] = inv;
      invS[(size_t)i*12 + h0 + t] = inv;
    }
  }
  if (ohalf == 1) {
    #pragma unroll
    for (int h = 0; h < 12; ++h) comb[h][oc] = oacc[h];
  }
  __syncthreads();
  if (ohalf == 0) {
    float* f = feat + (size_t)i*2112 + 576;
    #pragma unroll
    for (int h = 0; h < 12; ++h)
      f[h*128 + oc] = (oacc[h] + comb[h][oc]) * inv_sh[h];
  }
}

// ---------------- attn @ [vs | v_pt] per head -- b128 LDS reads, j-split ----
// grid (12,48,2). Block z handles j in [z*384, z*384+384) (3 tiles); partial
// acc written as float4 to pav[z][h][i][40]; reduce_sv sums the 2 partials.
__global__ __launch_bounds__(256) void res_sv_pt_kernel(
    const float* __restrict__ Pbuf, const float* __restrict__ invS,
    const float* __restrict__ Vpack, float* __restrict__ pav)
{
  __shared__ __align__(16) float at[16][132];
  __shared__ __align__(16) float vt[128][44];
  const int h = blockIdx.x;
  const int i0 = blockIdx.y * 16;
  const int z = blockIdx.z;
  const int tid = threadIdx.x;
  const int tm = tid / 10, tn = tid - tm*10;   // valid when tid < 160
  float acc[4] = {};
  for (int j0 = z*384; j0 < z*384 + 384; j0 += 128) {
    for (int t = tid; t < 16*32; t += 256) {
      int ii = t >> 5, jf = t & 31;
      float4 v = *(const float4*)(Pbuf + (size_t)h*NN + (size_t)(i0+ii)*N_RES + j0 + jf*4);
      float inv = invS[(size_t)(i0+ii)*12 + h];
      at[ii][jf*4+0] = v.x * inv;
      at[ii][jf*4+1] = v.y * inv;
      at[ii][jf*4+2] = v.z * inv;
      at[ii][jf*4+3] = v.w * inv;
    }
    for (int t = tid; t < 128*40; t += 256) {
      int jj = t / 40, c = t - jj*40;
      vt[jj][c] = Vpack[((size_t)(j0+jj)*12 + h)*40 + c];
    }
    __syncthreads();
    if (tid < 160) {
      #pragma unroll 4
      for (int jj0 = 0; jj0 < 128; jj0 += 4) {
        float4 a4 = *(const float4*)&at[tm][jj0];
        float4 v0 = *(const float4*)&vt[jj0+0][tn*4];
        float4 v1 = *(const float4*)&vt[jj0+1][tn*4];
        float4 v2 = *(const float4*)&vt[jj0+2][tn*4];
        float4 v3 = *(const float4*)&vt[jj0+3][tn*4];
        acc[0] = fmaf(a4.x, v0.x, acc[0]);
        acc[1] = fmaf(a4.x, v0.y, acc[1]);
        acc[2] = fmaf(a4.x, v0.z, acc[2]);
        acc[3] = fmaf(a4.x, v0.w, acc[3]);
        acc[0] = fmaf(a4.y, v1.x, acc[0]);
        acc[1] = fmaf(a4.y, v1.y, acc[1]);
        acc[2] = fmaf(a4.y, v1.z, acc[2]);
        acc[3] = fmaf(a4.y, v1.w, acc[3]);
        acc[0] = fmaf(a4.z, v2.x, acc[0]);
        acc[1] = fmaf(a4.z, v2.y, acc[1]);
        acc[2] = fmaf(a4.z, v2.z, acc[2]);
        acc[3] = fmaf(a4.z, v2.w, acc[3]);
        acc[0] = fmaf(a4.w, v3.x, acc[0]);
        acc[1] = fmaf(a4.w, v3.y, acc[1]);
        acc[2] = fmaf(a4.w, v3.z, acc[2]);
        acc[3] = fmaf(a4.w, v3.w, acc[3]);
      }
    }
    __syncthreads();
  }
  if (tid < 160) {
    const int i = i0 + tm;
    float* pv = pav + (((size_t)z*12 + h)*768 + i)*40 + tn*4;
    *(float4*)pv = make_float4(acc[0], acc[1], acc[2], acc[3]);
  }
}

// ---------------- point epilogue --------------------------------------------
__global__ __launch_bounds__(256) void pt_epilogue_kernel(
    const float* __restrict__ rpt,
    const float* __restrict__ rot, const float* __restrict__ tra,
    float* __restrict__ feat)
{
  int idx = blockIdx.x * 256 + threadIdx.x;
  if (idx >= N_RES * 96) return;
  int i = idx / 96, m = idx - i*96;
  int h = m >> 3, p = m & 7;
  const float* rp = rpt + ((size_t)i*NHEAD + h)*24 + p;
  float gx = rp[0]  - tra[i];
  float gy = rp[8]  - tra[N_RES + i];
  float gz = rp[16] - tra[2*N_RES + i];
  float lx = rot[0*N_RES+i]*gx + rot[3*N_RES+i]*gy + rot[6*N_RES+i]*gz;
  float ly = rot[1*N_RES+i]*gx + rot[4*N_RES+i]*gy + rot[7*N_RES+i]*gz;
  float lz = rot[2*N_RES+i]*gx + rot[5*N_RES+i]*gy + rot[8*N_RES+i]*gz;
  float dist = sqrtf(1e-8f + lx*lx + ly*ly + lz*lz);
  float* f = feat + (size_t)i*2112 + 192;
  f[m]       = lx;
  f[96 + m]  = ly;
  f[192 + m] = lz;
  f[288 + m] = dist;
}

extern "C" void kernel_launch(void* const* d_in, const int* in_sizes, int n_in,
                              void* d_out, int out_size, void* d_ws, size_t ws_size,
                              hipStream_t stream)
{
  const float* in1d = (const float*)d_in[0];
  const float* in2d = (const float*)d_in[1];
  const float* mask = (const float*)d_in[2];
  const float* rot  = (const float*)d_in[3];
  const float* tra  = (const float*)d_in[4];
  const float* wq   = (const float*)d_in[5];
  const float* bq   = (const float*)d_in[6];
  const float* wkv  = (const float*)d_in[7];
  const float* bkv  = (const float*)d_in[8];
  const float* wqp  = (const float*)d_in[9];
  const float* bqp  = (const float*)d_in[10];
  const float* wkvp = (const float*)d_in[11];
  const float* bkvp = (const float*)d_in[12];
  const float* tpw  = (const float*)d_in[13];
  const float* w2d  = (const float*)d_in[14];
  const float* b2d  = (const float*)d_in[15];
  const float* wout = (const float*)d_in[16];
  const float* bout = (const float*)d_in[17];
  float* out = (float*)d_out;

  float* ws = (float*)d_ws;
  float* Upack    = ws;                  // 294912
  float* Kpack    = ws + 294912;         // 294912  -> 589824
  float* Vpack    = ws + 589824;         // 368640  -> 958464
  float* wT       = ws + 958464;         // 1536    -> 960000
  float* feat     = ws + 960000;         // 1622016 -> 2582016
  float* invS     = ws + 2582016;        // 9216    -> 2591232
  float* rpt      = ws + 2591232;        // 221184  -> 2812416
  // region X at 2812416: proj_all(884736) | B_all(442368) | bias_all(1152) |
  //                      part_proj(1769472, ends 5910144)
  float* proj_all = ws + 2812416;        // dead after point_pack
  float* B_all    = ws + 3697152;        // dead after proj reduce
  float* bias_all = ws + 4139520;        // dead after proj reduce
  float* part_proj= ws + 4140672;        // 2*884736 (dead after proj reduce)
  // logits aliases region X (written by logits_sp AFTER point_pack)
  float* logits   = ws + 2812416;        // 7077888 -> 9890304
  float* part     = ws + 2812416;        // 12*294912 = 3538944 <= 7077888 (alias)
  float* pav      = ws + 9890304;        // 2*12*768*40 = 737280 -> 10627584
  // high-water: 10627584 floats = 42.5 MB (<= 44.9 MB proven)

  pack_b_kernel<<<432, 256, 0, stream>>>(wq, wkv, wqp, wkvp, B_all);
  pack_small_kernel<<<11, 256, 0, stream>>>(bq, bkv, bqp, bkvp, w2d, bias_all, wT);
  // projection GEMM, split-K z=2 into part_proj, then reduce+bias
  gemm_kernel<<<dim3(18,12,2), 256, 0, stream>>>(in1d, 384, B_all, 1152, nullptr,
                                                 part_proj, 1152, 768, 384, 192);
  reduce_proj_kernel<<<864, 256, 0, stream>>>(part_proj, bias_all, proj_all);
  point_pack_kernel<<<36, 256, 0, stream>>>(proj_all, rot, tra, tpw, b2d, mask,
                                            Upack, Kpack, Vpack);
  logits_sp_kernel<<<dim3(12,12,12), 256, 0, stream>>>(Upack, Kpack, logits);
  fused_attn_kernel<<<N_RES, 256, 0, stream>>>(in2d, wT, logits, invS, feat);
  res_sv_pt_kernel<<<dim3(12,48,2), 256, 0, stream>>>(logits, invS, Vpack, pav);
  reduce_sv_kernel<<<360, 256, 0, stream>>>(pav, feat, rpt);
  pt_epilogue_kernel<<<288, 256, 0, stream>>>(rpt, rot, tra, feat);
  gemm_kernel<<<dim3(6,12,OUT_SPLIT), 256, 0, stream>>>(feat, 2112, wout, 384, nullptr,
                                                        part, 384, 768, 2112, 176);
  reduce_out_kernel<<<288, 256, 0, stream>>>(part, bout, out);
}

// Round 26
// 246.256 us; speedup vs baseline: 1.3963x; 1.0021x over previous
//
#include <hip/hip_runtime.h>
#include <cstdint>
#include <cstddef>

// InvariantPointAttention N=768, H=12, C=384, PD=128, SQK=SV=16, PQK=4, PV=8.
// Round 26: R25 base (246.8us proven). Final knob in the proven class:
// output GEMM split-K z=12 -> z=22 (kPerSplit=96, 1584 blocks = 6.2/CU).
// All else frozen (fused = R16, logits_sp = R22, res_sv_pt = R25 j-split).

#define N_RES 768
#define NHEAD 12
#define NN (768*768)
#define OUT_SPLIT 22

__device__ __forceinline__ float softplusf_(float x) {
  return (x > 20.f) ? x : log1pf(__expf(x));
}

// ---------------- pack B_all[384][1152] from 4 weight mats ------------------
__global__ __launch_bounds__(256) void pack_b_kernel(
    const float* __restrict__ wq, const float* __restrict__ wkv,
    const float* __restrict__ wqp, const float* __restrict__ wkvp,
    float* __restrict__ B_all)
{
  int idx4 = blockIdx.x * 256 + threadIdx.x;   // 110592 units
  int k = idx4 / 288;
  int n = (idx4 - k*288) * 4;
  float4 v;
  if (n < 192)       v = *(const float4*)(wq   + (size_t)k*192 + n);
  else if (n < 576)  v = *(const float4*)(wkv  + (size_t)k*384 + (n-192));
  else if (n < 720)  v = *(const float4*)(wqp  + (size_t)k*144 + (n-576));
  else               v = *(const float4*)(wkvp + (size_t)k*432 + (n-720));
  *(float4*)(B_all + (size_t)k*1152 + n) = v;
}

// ---------------- pack bias_all[1152] + wT[12][128] -------------------------
__global__ __launch_bounds__(256) void pack_small_kernel(
    const float* __restrict__ bq, const float* __restrict__ bkv,
    const float* __restrict__ bqp, const float* __restrict__ bkvp,
    const float* __restrict__ w2d,
    float* __restrict__ bias_all, float* __restrict__ wT)
{
  int idx = blockIdx.x * 256 + threadIdx.x;
  if (idx < 1152) {
    float v;
    if (idx < 192)      v = bq[idx];
    else if (idx < 576) v = bkv[idx-192];
    else if (idx < 720) v = bqp[idx-576];
    else                v = bkvp[idx-720];
    bias_all[idx] = v;
  } else if (idx < 2688) {
    int t = idx - 1152;
    int h = t >> 7, c = t & 127;
    wT[h*128 + c] = 0.5773502691896258f * w2d[c*12 + h];
  }
}

// ---------------- tiled GEMM, optional split-K ------------------------------
__global__ __launch_bounds__(256) void gemm_kernel(
    const float* __restrict__ A, int lda,
    const float* __restrict__ B, int ldb,
    const float* __restrict__ bias,
    float* __restrict__ C, int ldc,
    int M, int K, int kPerSplit)
{
  __shared__ float As[16][68];
  __shared__ float Bs[16][68];
  const int tid = threadIdx.x;
  const int m0 = blockIdx.y * 64, n0 = blockIdx.x * 64;
  const int kbeg = blockIdx.z * kPerSplit;
  const int kend = kbeg + kPerSplit;
  const int tn = tid & 15, tm = tid >> 4;
  float acc[4][4] = {};
  for (int k0 = kbeg; k0 < kend; k0 += 16) {
    {
      int idx = tid * 4;
      int m = idx >> 4, kk = idx & 15;
      float4 a = *(const float4*)(A + (size_t)(m0+m)*lda + k0 + kk);
      As[kk+0][m] = a.x; As[kk+1][m] = a.y; As[kk+2][m] = a.z; As[kk+3][m] = a.w;
    }
    {
      int kk = tid >> 4, n = (tid & 15) * 4;
      float4 b = *(const float4*)(B + (size_t)(k0+kk)*ldb + n0 + n);
      *(float4*)&Bs[kk][n] = b;
    }
    __syncthreads();
    #pragma unroll
    for (int k = 0; k < 16; ++k) {
      float4 a = *(const float4*)&As[k][tm*4];
      float4 b = *(const float4*)&Bs[k][tn*4];
      acc[0][0]=fmaf(a.x,b.x,acc[0][0]); acc[0][1]=fmaf(a.x,b.y,acc[0][1]);
      acc[0][2]=fmaf(a.x,b.z,acc[0][2]); acc[0][3]=fmaf(a.x,b.w,acc[0][3]);
      acc[1][0]=fmaf(a.y,b.x,acc[1][0]); acc[1][1]=fmaf(a.y,b.y,acc[1][1]);
      acc[1][2]=fmaf(a.y,b.z,acc[1][2]); acc[1][3]=fmaf(a.y,b.w,acc[1][3]);
      acc[2][0]=fmaf(a.z,b.x,acc[2][0]); acc[2][1]=fmaf(a.z,b.y,acc[2][1]);
      acc[2][2]=fmaf(a.z,b.z,acc[2][2]); acc[2][3]=fmaf(a.z,b.w,acc[2][3]);
      acc[3][0]=fmaf(a.w,b.x,acc[3][0]); acc[3][1]=fmaf(a.w,b.y,acc[3][1]);
      acc[3][2]=fmaf(a.w,b.z,acc[3][2]); acc[3][3]=fmaf(a.w,b.w,acc[3][3]);
    }
    __syncthreads();
  }
  float* Cp = C + (size_t)blockIdx.z * M * ldc;
  if (gridDim.z == 1) {
    #pragma unroll
    for (int r = 0; r < 4; ++r) {
      float* cp = Cp + (size_t)(m0 + tm*4 + r)*ldc + n0 + tn*4;
      #pragma unroll
      for (int c = 0; c < 4; ++c) cp[c] = acc[r][c] + bias[n0 + tn*4 + c];
    }
  } else {
    #pragma unroll
    for (int r = 0; r < 4; ++r) {
      float* cp = Cp + (size_t)(m0 + tm*4 + r)*ldc + n0 + tn*4;
      #pragma unroll
      for (int c = 0; c < 4; ++c) cp[c] = acc[r][c];
    }
  }
}

// ---------------- split-K reduce + bias for the output GEMM (22 partials) ---
__global__ __launch_bounds__(256) void reduce_out_kernel(
    const float* __restrict__ part, const float* __restrict__ bout,
    float* __restrict__ out)
{
  int idx4 = blockIdx.x * 256 + threadIdx.x;   // 73728 units
  if (idx4 >= 73728) return;
  int n4 = idx4 % 96;
  float4 a = *(const float4*)(bout + n4*4);
  #pragma unroll
  for (int z = 0; z < OUT_SPLIT; ++z) {
    float4 p = *(const float4*)(part + (size_t)z*294912 + (size_t)idx4*4);
    a.x += p.x; a.y += p.y; a.z += p.z; a.w += p.w;
  }
  *(float4*)(out + (size_t)idx4*4) = a;
}

// ---------------- split-K reduce + bias for the proj GEMM (2 partials) ------
__global__ __launch_bounds__(256) void reduce_proj_kernel(
    const float* __restrict__ part, const float* __restrict__ bias,
    float* __restrict__ proj)
{
  int idx4 = blockIdx.x * 256 + threadIdx.x;   // 221184 units
  if (idx4 >= 221184) return;
  size_t off = (size_t)idx4 * 4;
  int n = (int)(off % 1152);
  float4 a = *(const float4*)(bias + n);
  float4 p0 = *(const float4*)(part + off);
  float4 p1 = *(const float4*)(part + 884736 + off);
  a.x += p0.x + p1.x;
  a.y += p0.y + p1.y;
  a.z += p0.z + p1.z;
  a.w += p0.w + p1.w;
  *(float4*)(proj + off) = a;
}

// ---------------- reduce_sv: sum 2 j-partials into feat/rpt -----------------
__global__ __launch_bounds__(256) void reduce_sv_kernel(
    const float* __restrict__ pav, float* __restrict__ feat,
    float* __restrict__ rpt)
{
  int idx4 = blockIdx.x * 256 + threadIdx.x;   // 92160 float4 units
  if (idx4 >= 92160) return;
  int col4 = idx4 % 10;
  int rest = idx4 / 10;
  int i = rest % 768;
  int h = rest / 768;
  size_t o0 = ((size_t)h*768 + i)*40 + col4*4;
  size_t o1 = ((size_t)(12 + h)*768 + i)*40 + col4*4;
  float4 p0 = *(const float4*)(pav + o0);
  float4 p1 = *(const float4*)(pav + o1);
  float4 a = make_float4(p0.x + p1.x, p0.y + p1.y, p0.z + p1.z, p0.w + p1.w);
  int col = col4 * 4;
  if (col < 16) {
    *(float4*)(feat + (size_t)i*2112 + h*16 + col) = a;
  } else {
    *(float4*)(rpt + ((size_t)i*NHEAD + h)*24 + (col - 16)) = a;
  }
}

// ---------------- build packed U/K/V vectors --------------------------------
// U[h][i][32]: [sw*qs(16), pw*qpt(12), ci, 50*mi, -0.5*pw, 0]
// K[h][j][32]: [ks(16), kpt(12), 1, mj, kn, 0]
// V[j][h][40]: [vs(16), vpt(24, d*8+p)]
__global__ __launch_bounds__(256) void point_pack_kernel(
    const float* __restrict__ proj, const float* __restrict__ rot,
    const float* __restrict__ tra, const float* __restrict__ tpw,
    const float* __restrict__ b2d, const float* __restrict__ mask,
    float* __restrict__ Upack, float* __restrict__ Kpack, float* __restrict__ Vpack)
{
  int idx = blockIdx.x * 256 + threadIdx.x;
  if (idx >= N_RES * NHEAD) return;
  int i = idx / NHEAD, h = idx - i*NHEAD;
  float R[9], T[3];
  #pragma unroll
  for (int r = 0; r < 9; ++r) R[r] = rot[r*N_RES + i];
  #pragma unroll
  for (int d = 0; d < 3; ++d) T[d] = tra[d*N_RES + i];
  const float pw = 0.13608276348795434f * softplusf_(tpw[h]); // sqrt(1/54)*sp
  const float sw = 0.14433756729740643f;                      // sqrt(1/48)
  const float s3 = 0.5773502691896258f;                       // sqrt(1/3)
  const float* prow = proj + (size_t)i * 1152;
  float* U  = Upack + ((size_t)h * N_RES + i) * 32;
  float* Kp = Kpack + ((size_t)h * N_RES + i) * 32;
  float* Vp = Vpack + (size_t)idx * 40;
  #pragma unroll
  for (int c = 0; c < 16; ++c) U[c]  = sw * prow[h*16 + c];
  #pragma unroll
  for (int c = 0; c < 16; ++c) Kp[c] = prow[192 + h*32 + c];
  #pragma unroll
  for (int c = 0; c < 16; ++c) Vp[c] = prow[192 + h*32 + 16 + c];
  float qn = 0.f;
  #pragma unroll
  for (int p = 0; p < 4; ++p) {
    float x = prow[576      + h*4 + p];
    float y = prow[576 + 48 + h*4 + p];
    float z = prow[576 + 96 + h*4 + p];
    #pragma unroll
    for (int d = 0; d < 3; ++d) {
      float v = R[3*d]*x + R[3*d+1]*y + R[3*d+2]*z + T[d];
      U[16 + d*4 + p] = pw * v;
      qn += v*v;
    }
  }
  float kn = 0.f;
  #pragma unroll
  for (int m = 0; m < 12; ++m) {
    float x = prow[720       + h*12 + m];
    float y = prow[720 + 144 + h*12 + m];
    float z = prow[720 + 288 + h*12 + m];
    #pragma unroll
    for (int d = 0; d < 3; ++d) {
      float v = R[3*d]*x + R[3*d+1]*y + R[3*d+2]*z + T[d];
      if (m < 4) { Kp[16 + d*4 + m] = v; kn += v*v; }
      else       { Vp[16 + d*8 + (m-4)] = v; }
    }
  }
  U[28] = -0.5f*pw*qn + s3*b2d[h] - 50.f;  U[29] = 50.f * mask[i];
  U[30] = -0.5f*pw;                        U[31] = 0.f;
  Kp[28] = 1.f;   Kp[29] = mask[i];
  Kp[30] = kn;    Kp[31] = 0.f;
}

// ---------------- scalar+point logits: Lsp[h] = U[h] @ K[h]^T (rank 32) -----
// k-major LDS tiles [32][68]: 2x ds_read_b128 per k (R22 proven).
__global__ __launch_bounds__(256) void logits_sp_kernel(
    const float* __restrict__ Upack, const float* __restrict__ Kpack,
    float* __restrict__ Lsp)
{
  __shared__ __align__(16) float Ut[32][68];
  __shared__ __align__(16) float Kt[32][68];
  const int h = blockIdx.z;
  const int i0 = blockIdx.y * 64, j0 = blockIdx.x * 64;
  const int tid = threadIdx.x;
  for (int t = tid; t < 512; t += 256) {
    int row = t >> 3, c4 = (t & 7) * 4;
    float4 u = *(const float4*)(Upack + ((size_t)h*N_RES + i0 + row)*32 + c4);
    float4 k = *(const float4*)(Kpack + ((size_t)h*N_RES + j0 + row)*32 + c4);
    Ut[c4+0][row] = u.x; Ut[c4+1][row] = u.y; Ut[c4+2][row] = u.z; Ut[c4+3][row] = u.w;
    Kt[c4+0][row] = k.x; Kt[c4+1][row] = k.y; Kt[c4+2][row] = k.z; Kt[c4+3][row] = k.w;
  }
  __syncthreads();
  const int tn = tid & 15, tm = tid >> 4;
  float acc[4][4] = {};
  #pragma unroll
  for (int k = 0; k < 32; ++k) {
    float4 a = *(const float4*)&Ut[k][tm*4];
    float4 b = *(const float4*)&Kt[k][tn*4];
    acc[0][0]=fmaf(a.x,b.x,acc[0][0]); acc[0][1]=fmaf(a.x,b.y,acc[0][1]);
    acc[0][2]=fmaf(a.x,b.z,acc[0][2]); acc[0][3]=fmaf(a.x,b.w,acc[0][3]);
    acc[1][0]=fmaf(a.y,b.x,acc[1][0]); acc[1][1]=fmaf(a.y,b.y,acc[1][1]);
    acc[1][2]=fmaf(a.y,b.z,acc[1][2]); acc[1][3]=fmaf(a.y,b.w,acc[1][3]);
    acc[2][0]=fmaf(a.z,b.x,acc[2][0]); acc[2][1]=fmaf(a.z,b.y,acc[2][1]);
    acc[2][2]=fmaf(a.z,b.z,acc[2][2]); acc[2][3]=fmaf(a.z,b.w,acc[2][3]);
    acc[3][0]=fmaf(a.w,b.x,acc[3][0]); acc[3][1]=fmaf(a.w,b.y,acc[3][1]);
    acc[3][2]=fmaf(a.w,b.z,acc[3][2]); acc[3][3]=fmaf(a.w,b.w,acc[3][3]);
  }
  #pragma unroll
  for (int r = 0; r < 4; ++r) {
    float4 v = make_float4(acc[r][0], acc[r][1], acc[r][2], acc[r][3]);
    *(float4*)(Lsp + (size_t)h*NN + (size_t)(i0 + tm*4 + r)*N_RES + j0 + tn*4) = v;
  }
}

// ---------------- fused: coalesced att2d + exp + res2d (R16 VERBATIM) -------
__global__ __launch_bounds__(256) void fused_attn_kernel(
    const float* __restrict__ in2d, const float* __restrict__ wT,
    float* __restrict__ logits,     // in: Lsp, out: P = exp(logit) (in-place)
    float* __restrict__ invS, float* __restrict__ feat)
{
  __shared__ __align__(16) float wTs[12][128];   // 6 KB
  __shared__ __align__(16) float Pt[128][12];    // 6 KB
  __shared__ float comb[12][128];                // 6 KB
  __shared__ float inv_sh[12];
  const int i = blockIdx.x;
  const int tid = threadIdx.x;
  const int wave = tid >> 6, lane = tid & 63;
  const int h0 = wave * 3;
  const int g = lane >> 2, t = lane & 3;
  for (int u = tid; u < 1536; u += 256) wTs[u >> 7][u & 127] = wT[u];
  __syncthreads();
  float s_run = 0.f;                 // head h0+t (t<3); t==3 unused
  const int oc = tid & 127, ohalf = tid >> 7;
  float oacc[12];
  #pragma unroll
  for (int h = 0; h < 12; ++h) oacc[h] = 0.f;

  for (int jt = 0; jt < 6; ++jt) {
    const int j0 = jt * 128;
    // ---- att2d + logits + exp: 8 rounds x 16 j ----
    #pragma unroll 2
    for (int r8 = 0; r8 < 8; ++r8) {
      const int j = j0 + r8*16 + g;
      const float* xrow = in2d + ((size_t)i*N_RES + j) * 128;
      float t0 = 0.f, t1 = 0.f, t2 = 0.f;
      #pragma unroll
      for (int c = 0; c < 8; ++c) {
        const int ch = c*16 + t*4;
        float4 x  = *(const float4*)(xrow + ch);
        float4 wa = *(const float4*)&wTs[h0+0][ch];
        float4 wb = *(const float4*)&wTs[h0+1][ch];
        float4 wc = *(const float4*)&wTs[h0+2][ch];
        t0 = fmaf(x.x,wa.x, fmaf(x.y,wa.y, fmaf(x.z,wa.z, fmaf(x.w,wa.w, t0))));
        t1 = fmaf(x.x,wb.x, fmaf(x.y,wb.y, fmaf(x.z,wb.z, fmaf(x.w,wb.w, t1))));
        t2 = fmaf(x.x,wc.x, fmaf(x.y,wc.y, fmaf(x.z,wc.z, fmaf(x.w,wc.w, t2))));
      }
      // butterfly over the 4-lane group
      t0 += __shfl_xor(t0, 1); t0 += __shfl_xor(t0, 2);
      t1 += __shfl_xor(t1, 1); t1 += __shfl_xor(t1, 2);
      t2 += __shfl_xor(t2, 1); t2 += __shfl_xor(t2, 2);
      if (t < 3) {
        float td = (t == 0) ? t0 : ((t == 1) ? t1 : t2);
        const size_t off = (size_t)(h0+t)*NN + (size_t)i*N_RES + j;
        float l = logits[off] + td;
        float p = __expf(l);
        logits[off] = p;              // store P in place
        s_run += p;
        Pt[r8*16 + g][h0 + t] = p;
      }
    }
    __syncthreads();
    // ---- res2d: 128 rows, thread handles rows [ohalf*64, +64), channel oc --
    {
      const float* xb = in2d + ((size_t)i*N_RES + j0 + ohalf*64) * 128 + oc;
      #pragma unroll 4
      for (int jj = 0; jj < 64; ++jj) {
        int row = ohalf*64 + jj;
        float x = xb[(size_t)jj * 128];
        float4 p0 = *(const float4*)&Pt[row][0];
        float4 p1 = *(const float4*)&Pt[row][4];
        float4 p2 = *(const float4*)&Pt[row][8];
        oacc[0] = fmaf(p0.x, x, oacc[0]);
        oacc[1] = fmaf(p0.y, x, oacc[1]);
        oacc[2] = fmaf(p0.z, x, oacc[2]);
        oacc[3] = fmaf(p0.w, x, oacc[3]);
        oacc[4] = fmaf(p1.x, x, oacc[4]);
        oacc[5] = fmaf(p1.y, x, oacc[5]);
        oacc[6] = fmaf(p1.z, x, oacc[6]);
        oacc[7] = fmaf(p1.w, x, oacc[7]);
        oacc[8] = fmaf(p2.x, x, oacc[8]);
        oacc[9] = fmaf(p2.y, x, oacc[9]);
        oacc[10] = fmaf(p2.z, x, oacc[10]);
        oacc[11] = fmaf(p2.w, x, oacc[11]);
      }
    }
    __syncthreads();   // Pt consumed; safe to overwrite next iter
  }
  // ---- denominators: butterfly over g-bits (4,8,16,32), lanes 0..2 write ---
  {
    float s = s_run;
    s += __shfl_xor(s, 4);
    s += __shfl_xor(s, 8);
    s += __shfl_xor(s, 16);
    s += __shfl_xor(s, 32);
    if (g == 0 && t < 3) {
      float inv = 1.f / s;
      inv_sh[h0 + t] = inv;
      invS[(size_t)i*12 + h0 + t] = inv;
    }
  }
  if (ohalf == 1) {
    #pragma unroll
    for (int h = 0; h < 12; ++h) comb[h][oc] = oacc[h];
  }
  __syncthreads();
  if (ohalf == 0) {
    float* f = feat + (size_t)i*2112 + 576;
    #pragma unroll
    for (int h = 0; h < 12; ++h)
      f[h*128 + oc] = (oacc[h] + comb[h][oc]) * inv_sh[h];
  }
}

// ---------------- attn @ [vs | v_pt] per head -- b128 LDS reads, j-split ----
// grid (12,48,2). Block z handles j in [z*384, z*384+384) (3 tiles); partial
// acc written as float4 to pav[z][h][i][40]; reduce_sv sums the 2 partials.
__global__ __launch_bounds__(256) void res_sv_pt_kernel(
    const float* __restrict__ Pbuf, const float* __restrict__ invS,
    const float* __restrict__ Vpack, float* __restrict__ pav)
{
  __shared__ __align__(16) float at[16][132];
  __shared__ __align__(16) float vt[128][44];
  const int h = blockIdx.x;
  const int i0 = blockIdx.y * 16;
  const int z = blockIdx.z;
  const int tid = threadIdx.x;
  const int tm = tid / 10, tn = tid - tm*10;   // valid when tid < 160
  float acc[4] = {};
  for (int j0 = z*384; j0 < z*384 + 384; j0 += 128) {
    for (int t = tid; t < 16*32; t += 256) {
      int ii = t >> 5, jf = t & 31;
      float4 v = *(const float4*)(Pbuf + (size_t)h*NN + (size_t)(i0+ii)*N_RES + j0 + jf*4);
      float inv = invS[(size_t)(i0+ii)*12 + h];
      at[ii][jf*4+0] = v.x * inv;
      at[ii][jf*4+1] = v.y * inv;
      at[ii][jf*4+2] = v.z * inv;
      at[ii][jf*4+3] = v.w * inv;
    }
    for (int t = tid; t < 128*40; t += 256) {
      int jj = t / 40, c = t - jj*40;
      vt[jj][c] = Vpack[((size_t)(j0+jj)*12 + h)*40 + c];
    }
    __syncthreads();
    if (tid < 160) {
      #pragma unroll 4
      for (int jj0 = 0; jj0 < 128; jj0 += 4) {
        float4 a4 = *(const float4*)&at[tm][jj0];
        float4 v0 = *(const float4*)&vt[jj0+0][tn*4];
        float4 v1 = *(const float4*)&vt[jj0+1][tn*4];
        float4 v2 = *(const float4*)&vt[jj0+2][tn*4];
        float4 v3 = *(const float4*)&vt[jj0+3][tn*4];
        acc[0] = fmaf(a4.x, v0.x, acc[0]);
        acc[1] = fmaf(a4.x, v0.y, acc[1]);
        acc[2] = fmaf(a4.x, v0.z, acc[2]);
        acc[3] = fmaf(a4.x, v0.w, acc[3]);
        acc[0] = fmaf(a4.y, v1.x, acc[0]);
        acc[1] = fmaf(a4.y, v1.y, acc[1]);
        acc[2] = fmaf(a4.y, v1.z, acc[2]);
        acc[3] = fmaf(a4.y, v1.w, acc[3]);
        acc[0] = fmaf(a4.z, v2.x, acc[0]);
        acc[1] = fmaf(a4.z, v2.y, acc[1]);
        acc[2] = fmaf(a4.z, v2.z, acc[2]);
        acc[3] = fmaf(a4.z, v2.w, acc[3]);
        acc[0] = fmaf(a4.w, v3.x, acc[0]);
        acc[1] = fmaf(a4.w, v3.y, acc[1]);
        acc[2] = fmaf(a4.w, v3.z, acc[2]);
        acc[3] = fmaf(a4.w, v3.w, acc[3]);
      }
    }
    __syncthreads();
  }
  if (tid < 160) {
    const int i = i0 + tm;
    float* pv = pav + (((size_t)z*12 + h)*768 + i)*40 + tn*4;
    *(float4*)pv = make_float4(acc[0], acc[1], acc[2], acc[3]);
  }
}

// ---------------- point epilogue --------------------------------------------
__global__ __launch_bounds__(256) void pt_epilogue_kernel(
    const float* __restrict__ rpt,
    const float* __restrict__ rot, const float* __restrict__ tra,
    float* __restrict__ feat)
{
  int idx = blockIdx.x * 256 + threadIdx.x;
  if (idx >= N_RES * 96) return;
  int i = idx / 96, m = idx - i*96;
  int h = m >> 3, p = m & 7;
  const float* rp = rpt + ((size_t)i*NHEAD + h)*24 + p;
  float gx = rp[0]  - tra[i];
  float gy = rp[8]  - tra[N_RES + i];
  float gz = rp[16] - tra[2*N_RES + i];
  float lx = rot[0*N_RES+i]*gx + rot[3*N_RES+i]*gy + rot[6*N_RES+i]*gz;
  float ly = rot[1*N_RES+i]*gx + rot[4*N_RES+i]*gy + rot[7*N_RES+i]*gz;
  float lz = rot[2*N_RES+i]*gx + rot[5*N_RES+i]*gy + rot[8*N_RES+i]*gz;
  float dist = sqrtf(1e-8f + lx*lx + ly*ly + lz*lz);
  float* f = feat + (size_t)i*2112 + 192;
  f[m]       = lx;
  f[96 + m]  = ly;
  f[192 + m] = lz;
  f[288 + m] = dist;
}

extern "C" void kernel_launch(void* const* d_in, const int* in_sizes, int n_in,
                              void* d_out, int out_size, void* d_ws, size_t ws_size,
                              hipStream_t stream)
{
  const float* in1d = (const float*)d_in[0];
  const float* in2d = (const float*)d_in[1];
  const float* mask = (const float*)d_in[2];
  const float* rot  = (const float*)d_in[3];
  const float* tra  = (const float*)d_in[4];
  const float* wq   = (const float*)d_in[5];
  const float* bq   = (const float*)d_in[6];
  const float* wkv  = (const float*)d_in[7];
  const float* bkv  = (const float*)d_in[8];
  const float* wqp  = (const float*)d_in[9];
  const float* bqp  = (const float*)d_in[10];
  const float* wkvp = (const float*)d_in[11];
  const float* bkvp = (const float*)d_in[12];
  const float* tpw  = (const float*)d_in[13];
  const float* w2d  = (const float*)d_in[14];
  const float* b2d  = (const float*)d_in[15];
  const float* wout = (const float*)d_in[16];
  const float* bout = (const float*)d_in[17];
  float* out = (float*)d_out;

  float* ws = (float*)d_ws;
  float* Upack    = ws;                  // 294912
  float* Kpack    = ws + 294912;         // 294912  -> 589824
  float* Vpack    = ws + 589824;         // 368640  -> 958464
  float* wT       = ws + 958464;         // 1536    -> 960000
  float* feat     = ws + 960000;         // 1622016 -> 2582016
  float* invS     = ws + 2582016;        // 9216    -> 2591232
  float* rpt      = ws + 2591232;        // 221184  -> 2812416
  // region X at 2812416: proj_all(884736) | B_all(442368) | bias_all(1152) |
  //                      part_proj(1769472, ends 5910144)
  float* proj_all = ws + 2812416;        // dead after point_pack
  float* B_all    = ws + 3697152;        // dead after proj reduce
  float* bias_all = ws + 4139520;        // dead after proj reduce
  float* part_proj= ws + 4140672;        // 2*884736 (dead after proj reduce)
  // logits aliases region X (written by logits_sp AFTER point_pack)
  float* logits   = ws + 2812416;        // 7077888 -> 9890304
  float* part     = ws + 2812416;        // 22*294912 = 6488064 <= 7077888 (alias)
  float* pav      = ws + 9890304;        // 2*12*768*40 = 737280 -> 10627584
  // high-water: 10627584 floats = 42.5 MB (<= 44.9 MB proven)

  pack_b_kernel<<<432, 256, 0, stream>>>(wq, wkv, wqp, wkvp, B_all);
  pack_small_kernel<<<11, 256, 0, stream>>>(bq, bkv, bqp, bkvp, w2d, bias_all, wT);
  // projection GEMM, split-K z=2 into part_proj, then reduce+bias
  gemm_kernel<<<dim3(18,12,2), 256, 0, stream>>>(in1d, 384, B_all, 1152, nullptr,
                                                 part_proj, 1152, 768, 384, 192);
  reduce_proj_kernel<<<864, 256, 0, stream>>>(part_proj, bias_all, proj_all);
  point_pack_kernel<<<36, 256, 0, stream>>>(proj_all, rot, tra, tpw, b2d, mask,
                                            Upack, Kpack, Vpack);
  logits_sp_kernel<<<dim3(12,12,12), 256, 0, stream>>>(Upack, Kpack, logits);
  fused_attn_kernel<<<N_RES, 256, 0, stream>>>(in2d, wT, logits, invS, feat);
  res_sv_pt_kernel<<<dim3(12,48,2), 256, 0, stream>>>(logits, invS, Vpack, pav);
  reduce_sv_kernel<<<360, 256, 0, stream>>>(pav, feat, rpt);
  pt_epilogue_kernel<<<288, 256, 0, stream>>>(rpt, rot, tra, feat);
  gemm_kernel<<<dim3(6,12,OUT_SPLIT), 256, 0, stream>>>(feat, 2112, wout, 384, nullptr,
                                                        part, 384, 768, 2112, 96);
  reduce_out_kernel<<<288, 256, 0, stream>>>(part, bout, out);
}